// Round 1
// baseline (39990.713 us; speedup 1.0000x reference)
//
#include <hip/hip_runtime.h>
#include <math.h>

// ---------------- problem dims ----------------
#define DD    1024
#define TT    128
#define BB    256
#define NE    64
#define NCC   128
#define PPP   50
#define NCK   8
#define HH    512
#define G4    2048     // 4*HH
#define KREC  1536     // DD + HH
#define NROWS 32768    // BB*TT
#define K3PAD 3200     // padded K for phase2/3 GEMMs (3123 / 3173 -> 3200)

// ---------------- workspace layout (float offsets) ----------------
#define F_HSEQ  0ull            // [BB,TT,DD]   33,554,432   (later reused as delta3 [64,128,3200] = 26,214,400)
#define F_H3    33554432ull     // [64,128,1024] 8,388,608
#define F_WCAT  41943040ull     // [2][1536][2048] 6,291,456
#define F_BIASC 48234496ull     // [2][2048]
#define F_HST   48238592ull     // [2 buf][2 dir][BB][HH] 524,288
#define F_CST   48762880ull     // [2 dir][BB][HH] 262,144
#define F_S1WT  49025024ull     // [1024][1024]
#define F_CS    50073600ull     // [1024]
#define F_CSQ   50074624ull     // [1024]
#define F_BNM   50075648ull     // [1024]
#define F_BNI   50076672ull     // [1024]
#define F_ALPHA 50077696ull     // [BB*TT]
#define F_U     50110464ull     // [BB,DD]
#define F_W2T   50372608ull     // [3200][1024]
#define F_W3T   53649408ull     // [3200][1024]
#define F_CHE   56926208ull     // chunkEmb [64,8,1024]
#define F_D2    57450496ull     // delta2 [64,8,3200]
#define F_H2    59088896ull     // [64,8,1024]
#define F_BN2M  59613184ull     // [64,1024]
#define F_BN2I  59678720ull
#define F_EXTRA 59744256ull     // [64*8]
#define F_BN3M  59744768ull     // [64,1024]
#define F_BN3I  59810304ull
#define F_D3    F_HSEQ
#define WS_FLOATS 59875840ull   // ~239.5 MB

__device__ __forceinline__ float leakyf(float x) { return x >= 0.f ? x : 0.01f * x; }
__device__ __forceinline__ float sigmf(float x)  { return 1.f / (1.f + __expf(-x)); }

__device__ __forceinline__ float blk_sum(float v, float* s4) {
  for (int o = 32; o > 0; o >>= 1) v += __shfl_down(v, o);
  __syncthreads();
  if ((threadIdx.x & 63) == 0) s4[threadIdx.x >> 6] = v;
  __syncthreads();
  return s4[0] + s4[1] + s4[2] + s4[3];
}

// ---------------- transpose: dst[k*N+n] = (k<K) ? src[n*K+k] : 0, k in [0,KD) ----------------
__global__ __launch_bounds__(256) void k_transpose(const float* __restrict__ src,
                                                   float* __restrict__ dst,
                                                   int N, int K, int KD) {
  __shared__ float L[32][33];
  int k0 = blockIdx.x * 32;
  int n0 = blockIdx.y * 32;
  int tx = threadIdx.x & 31, ty = threadIdx.x >> 5;  // 32 x 8
#pragma unroll
  for (int ii = 0; ii < 4; ++ii) {
    int n = n0 + ty + ii * 8, k = k0 + tx;
    float v = 0.f;
    if (n < N && k < K) v = src[(size_t)n * K + k];
    L[ty + ii * 8][tx] = v;
  }
  __syncthreads();
#pragma unroll
  for (int ii = 0; ii < 4; ++ii) {
    int k = k0 + ty + ii * 8, n = n0 + tx;
    if (k < KD && n < N) dst[(size_t)k * N + n] = L[tx][ty + ii * 8];
  }
}

__global__ __launch_bounds__(256) void k_biasc(const float* __restrict__ bf1, const float* __restrict__ bf2,
                                               const float* __restrict__ bb1, const float* __restrict__ bb2,
                                               float* __restrict__ out) {
  int i = blockIdx.x * 256 + threadIdx.x;  // 4096
  if (i < G4) out[i] = bf1[i] + bf2[i];
  else        out[i] = bb1[i - G4] + bb2[i - G4];
}

// ---------------- fused LSTM step: gates = [x_t, h_t] @ Wcat + bias; cell update ----------------
// grid (16 btiles, 16 jtiles, 2 dirs), 256 threads, tile = 16 rows x (4 gates x 32 hcols)
__global__ __launch_bounds__(256, 2) void k_step(
    const float* __restrict__ X, const float* __restrict__ Wcat,
    const float* __restrict__ biasC, const int* __restrict__ lens,
    const float* __restrict__ Hcur, float* __restrict__ Hnext,
    float* __restrict__ Cst, float* __restrict__ Hseq, int t) {
  __shared__ float Bs[4][32][20];       // [gate][hcol][k(16,pad20)]
  __shared__ float gx[2][4][32][8];     // gate exchange for cell update
  const int tid = threadIdx.x;
  const int b0 = blockIdx.x * 16;
  const int j0 = blockIdx.y * 32;
  const int dir = blockIdx.z;
  const int rg = tid >> 7;              // 0..1 (row group of 8)
  const int cidx = tid & 127;
  const int g = cidx >> 5;              // gate 0..3
  const int tc = cidx & 31;             // hcol within tile

  const float* aX[8];
  const float* aH[8];
#pragma unroll
  for (int i = 0; i < 8; ++i) {
    int b = b0 + rg * 8 + i;
    int len = lens[b];
    int r = (dir == 0) ? t : ((t < len) ? (len - 1 - t) : t);
    aX[i] = X + ((size_t)b * TT + r) * DD;
    aH[i] = Hcur + ((size_t)dir * BB + b) * HH;
  }
  float acc[8];
  {
    float bv = biasC[dir * G4 + g * HH + j0 + tc];
#pragma unroll
    for (int i = 0; i < 8; ++i) acc[i] = bv;
  }
  const float* Wd = Wcat + (size_t)dir * KREC * G4;

#pragma unroll 1
  for (int k0 = 0; k0 < KREC; k0 += 16) {
    __syncthreads();
#pragma unroll
    for (int i = 0; i < 2; ++i) {
      int fidx = tid + i * 256;         // 0..511
      int kk = fidx >> 5;
      int rem = fidx & 31;
      int gg = rem >> 3;
      int ff = rem & 7;
      float4 w = *(const float4*)(Wd + (size_t)(k0 + kk) * G4 + gg * HH + j0 + ff * 4);
      Bs[gg][ff * 4 + 0][kk] = w.x;
      Bs[gg][ff * 4 + 1][kk] = w.y;
      Bs[gg][ff * 4 + 2][kk] = w.z;
      Bs[gg][ff * 4 + 3][kk] = w.w;
    }
    __syncthreads();
    if (k0 < DD) {
#pragma unroll
      for (int kq = 0; kq < 4; ++kq) {
        float4 b4 = *(const float4*)&Bs[g][tc][kq * 4];
#pragma unroll
        for (int i = 0; i < 8; ++i) {
          float4 a = *(const float4*)(aX[i] + k0 + kq * 4);
          acc[i] += a.x * b4.x + a.y * b4.y + a.z * b4.z + a.w * b4.w;
        }
      }
    } else {
      int koff = k0 - DD;
#pragma unroll
      for (int kq = 0; kq < 4; ++kq) {
        float4 b4 = *(const float4*)&Bs[g][tc][kq * 4];
#pragma unroll
        for (int i = 0; i < 8; ++i) {
          float4 a = *(const float4*)(aH[i] + koff + kq * 4);
          acc[i] += a.x * b4.x + a.y * b4.y + a.z * b4.z + a.w * b4.w;
        }
      }
    }
  }
  __syncthreads();
#pragma unroll
  for (int i = 0; i < 8; ++i) gx[rg][g][tc][i] = acc[i];
  __syncthreads();
#pragma unroll 1
  for (int cc = tid; cc < 512; cc += 256) {
    int row = cc >> 5;
    int jj = cc & 31;
    int rg2 = row >> 3, i2 = row & 7;
    float gi = gx[rg2][0][jj][i2];
    float gf = gx[rg2][1][jj][i2];
    float gc = gx[rg2][2][jj][i2];
    float go = gx[rg2][3][jj][i2];
    int b = b0 + row;
    int len = lens[b];
    bool m = (t < len);
    int j = j0 + jj;
    size_t sidx = ((size_t)dir * BB + b) * HH + j;
    float c_old = Cst[sidx];
    float h_old = Hcur[sidx];
    float ig = sigmf(gi);
    float fg = sigmf(gf);
    float cg = tanhf(gc);
    float og = sigmf(go);
    float c_new = fg * c_old + ig * cg;
    float h_new = og * tanhf(c_new);
    if (m) {
      Cst[sidx] = c_new;
      int ro = dir ? (len - 1 - t) : t;
      Hseq[((size_t)b * TT + ro) * DD + dir * HH + j] = h_new;
    }
    Hnext[sidx] = m ? h_new : h_old;
  }
}

// ---------------- generic 64x64 fp32 GEMM, A from global (L1 broadcast), B^T staged in LDS ----------------
// MODE 0: C = A@B + bias
// MODE 1: accumulate per-column sum / sumsq of (A@B + bias) into cs/csq (atomic)
// MODE 2: alpha[row] += sum_col leaky((z - bnm)*bni) * s2w[col]  (atomic)
template <int MODE>
__global__ __launch_bounds__(256) void k_gemm(
    const float* __restrict__ A, const float* __restrict__ Bt,
    const float* __restrict__ bias, float* __restrict__ C,
    int M, int N, int K,
    const float* __restrict__ bnm, const float* __restrict__ bni,
    const float* __restrict__ s2w, float* __restrict__ cs,
    float* __restrict__ csq, float* __restrict__ alpha) {
  __shared__ float Bs[64][20];
  __shared__ float red[64][17];
  const int tid = threadIdx.x;
  const int tx = tid & 15, ty = tid >> 4;
  const int m0 = blockIdx.x * 64, n0 = blockIdx.y * 64;
  float acc[4][4];
#pragma unroll
  for (int i = 0; i < 4; ++i)
#pragma unroll
    for (int j = 0; j < 4; ++j) acc[i][j] = bias[n0 + tx * 4 + j];
  const float* Ar0 = A + (size_t)(m0 + ty * 4 + 0) * K;
  const float* Ar1 = A + (size_t)(m0 + ty * 4 + 1) * K;
  const float* Ar2 = A + (size_t)(m0 + ty * 4 + 2) * K;
  const float* Ar3 = A + (size_t)(m0 + ty * 4 + 3) * K;
  const int skk = tid >> 4, sff = tid & 15;
#pragma unroll 1
  for (int k0 = 0; k0 < K; k0 += 16) {
    __syncthreads();
    {
      float4 w = *(const float4*)(Bt + (size_t)(k0 + skk) * N + n0 + sff * 4);
      Bs[sff * 4 + 0][skk] = w.x;
      Bs[sff * 4 + 1][skk] = w.y;
      Bs[sff * 4 + 2][skk] = w.z;
      Bs[sff * 4 + 3][skk] = w.w;
    }
    __syncthreads();
#pragma unroll
    for (int kq = 0; kq < 4; ++kq) {
      float4 a0 = *(const float4*)(Ar0 + k0 + kq * 4);
      float4 a1 = *(const float4*)(Ar1 + k0 + kq * 4);
      float4 a2 = *(const float4*)(Ar2 + k0 + kq * 4);
      float4 a3 = *(const float4*)(Ar3 + k0 + kq * 4);
#pragma unroll
      for (int j = 0; j < 4; ++j) {
        float4 b = *(const float4*)&Bs[tx * 4 + j][kq * 4];
        acc[0][j] += a0.x * b.x + a0.y * b.y + a0.z * b.z + a0.w * b.w;
        acc[1][j] += a1.x * b.x + a1.y * b.y + a1.z * b.z + a1.w * b.w;
        acc[2][j] += a2.x * b.x + a2.y * b.y + a2.z * b.z + a2.w * b.w;
        acc[3][j] += a3.x * b.x + a3.y * b.y + a3.z * b.z + a3.w * b.w;
      }
    }
  }
  if (MODE == 0) {
#pragma unroll
    for (int i = 0; i < 4; ++i) {
      float4 o;
      o.x = acc[i][0]; o.y = acc[i][1]; o.z = acc[i][2]; o.w = acc[i][3];
      *(float4*)(C + (size_t)(m0 + ty * 4 + i) * N + n0 + tx * 4) = o;
    }
  } else if (MODE == 1) {
    float cS[4], cQ[4];
#pragma unroll
    for (int j = 0; j < 4; ++j) {
      cS[j] = acc[0][j] + acc[1][j] + acc[2][j] + acc[3][j];
      cQ[j] = acc[0][j] * acc[0][j] + acc[1][j] * acc[1][j] +
              acc[2][j] * acc[2][j] + acc[3][j] * acc[3][j];
    }
    __syncthreads();
#pragma unroll
    for (int j = 0; j < 4; ++j) red[tx * 4 + j][ty] = cS[j];
    __syncthreads();
    if (tid < 64) {
      float s = 0;
#pragma unroll
      for (int y = 0; y < 16; ++y) s += red[tid][y];
      atomicAdd(&cs[n0 + tid], s);
    }
    __syncthreads();
#pragma unroll
    for (int j = 0; j < 4; ++j) red[tx * 4 + j][ty] = cQ[j];
    __syncthreads();
    if (tid < 64) {
      float s = 0;
#pragma unroll
      for (int y = 0; y < 16; ++y) s += red[tid][y];
      atomicAdd(&csq[n0 + tid], s);
    }
  } else {
    float rs0 = 0, rs1 = 0, rs2 = 0, rs3 = 0;
#pragma unroll
    for (int j = 0; j < 4; ++j) {
      int col = n0 + tx * 4 + j;
      float mc = bnm[col], ic = bni[col], wc = s2w[col];
      rs0 += leakyf((acc[0][j] - mc) * ic) * wc;
      rs1 += leakyf((acc[1][j] - mc) * ic) * wc;
      rs2 += leakyf((acc[2][j] - mc) * ic) * wc;
      rs3 += leakyf((acc[3][j] - mc) * ic) * wc;
    }
    __syncthreads();
    red[ty * 4 + 0][tx] = rs0;
    red[ty * 4 + 1][tx] = rs1;
    red[ty * 4 + 2][tx] = rs2;
    red[ty * 4 + 3][tx] = rs3;
    __syncthreads();
    if (tid < 64) {
      float s = 0;
#pragma unroll
      for (int x = 0; x < 16; ++x) s += red[tid][x];
      atomicAdd(&alpha[m0 + tid], s);
    }
  }
}

__global__ __launch_bounds__(256) void k_bnfinal(const float* __restrict__ cs, const float* __restrict__ csq,
                                                 float* __restrict__ bnm, float* __restrict__ bni, float invN) {
  int i = blockIdx.x * 256 + threadIdx.x;
  if (i < DD) {
    float m = cs[i] * invN;
    float v = csq[i] * invN - m * m;
    bnm[i] = m;
    bni[i] = rsqrtf(v + 1e-5f);
  }
}

// mask + normalize alpha per batch row:  alpha = (t<len ? a : 0) / (sum + 1e-9)
__global__ __launch_bounds__(128) void k_asum(float* __restrict__ alpha, const int* __restrict__ lens) {
  int b = blockIdx.x;
  int t = threadIdx.x;  // 128
  int len = lens[b];
  float v = (t < len) ? alpha[b * TT + t] : 0.f;
  float s = v;
  for (int o = 32; o > 0; o >>= 1) s += __shfl_down(s, o);
  __shared__ float sw[2];
  if ((t & 63) == 0) sw[t >> 6] = s;
  __syncthreads();
  float S = sw[0] + sw[1] + 1e-9f;
  alpha[b * TT + t] = v / S;
}

__global__ __launch_bounds__(256) void k_U(const float* __restrict__ Hseq,
                                           const float* __restrict__ alpha,
                                           float* __restrict__ U) {
  int b = blockIdx.x;
  int tid = threadIdx.x;
  __shared__ float al[TT];
  if (tid < TT) al[tid] = alpha[b * TT + tid];
  __syncthreads();
  float4 s = make_float4(0.f, 0.f, 0.f, 0.f);
  const float* Hb = Hseq + (size_t)b * TT * DD + tid * 4;
#pragma unroll 4
  for (int t = 0; t < TT; ++t) {
    float a = al[t];
    float4 h = *(const float4*)(Hb + (size_t)t * DD);
    s.x += a * h.x; s.y += a * h.y; s.z += a * h.z; s.w += a * h.w;
  }
  *(float4*)(U + (size_t)b * DD + tid * 4) = s;
}

// phase-2 chunk attention: scores -> softmax over 16 -> chunkEmb
__global__ __launch_bounds__(256) void k_p2a(const float* __restrict__ U,
                                             const int* __restrict__ emoI,
                                             const int* __restrict__ cauI,
                                             float* __restrict__ chunkEmb) {
  int e = blockIdx.x;
  int tid = threadIdx.x;
  __shared__ float emoS[DD];
  __shared__ float sc[NCK][16];
  const float* Ue = U + (size_t)emoI[e] * DD;
  for (int i = tid; i < DD; i += 256) emoS[i] = Ue[i];
  __syncthreads();
  int w = tid >> 6, lane = tid & 63;
  for (int p = w; p < 128; p += 4) {
    const float* y = U + (size_t)cauI[p] * DD;
    float s = 0;
    for (int d = lane; d < DD; d += 64) s += emoS[d] * y[d];
    for (int o = 32; o > 0; o >>= 1) s += __shfl_down(s, o);
    if (lane == 0) sc[p >> 4][p & 15] = s;
  }
  __syncthreads();
  if (tid < NCK) {
    float mx = -1e30f;
    for (int c = 0; c < 16; ++c) mx = fmaxf(mx, sc[tid][c]);
    float sum = 0;
    for (int c = 0; c < 16; ++c) {
      float ev = __expf(sc[tid][c] - mx);
      sc[tid][c] = ev;
      sum += ev;
    }
    float inv = 1.f / sum;
    for (int c = 0; c < 16; ++c) sc[tid][c] *= inv;
  }
  __syncthreads();
  int d = tid * 4;
  for (int nn = 0; nn < NCK; ++nn) {
    float4 s = make_float4(0.f, 0.f, 0.f, 0.f);
    for (int c = 0; c < 16; ++c) {
      float wc = sc[nn][c];
      float4 y = *(const float4*)(U + (size_t)cauI[nn * 16 + c] * DD + d);
      s.x += wc * y.x; s.y += wc * y.y; s.z += wc * y.z; s.w += wc * y.w;
    }
    *(float4*)(chunkEmb + ((size_t)e * NCK + nn) * DD + d) = s;
  }
}

// delta2 row builder: [emo | y | dist | emo*y | pos | 0-pad]
__global__ __launch_bounds__(256) void k_delta2(const float* __restrict__ U,
                                                const int* __restrict__ emoI,
                                                const float* __restrict__ chunkEmb,
                                                const float* __restrict__ pos,
                                                float* __restrict__ delta2) {
  int e = blockIdx.x >> 3, nn = blockIdx.x & 7;
  int tid = threadIdx.x;
  const float* emo = U + (size_t)emoI[e] * DD;
  const float* y = chunkEmb + ((size_t)e * NCK + nn) * DD;
  __shared__ float s4[4];
  float ds = 0;
  for (int d = tid; d < DD; d += 256) {
    float df = emo[d] - y[d];
    ds += df * df;
  }
  float dist = sqrtf(blk_sum(ds, s4));
  float* out = delta2 + ((size_t)e * NCK + nn) * K3PAD;
  for (int c = tid; c < K3PAD; c += 256) {
    float v;
    if (c < 1024) v = emo[c];
    else if (c < 2048) v = y[c - 1024];
    else if (c == 2048) v = dist;
    else if (c < 3073) { int d = c - 2049; v = emo[d] * y[d]; }
    else if (c < 3123) v = pos[((size_t)e * NCK + nn) * PPP + (c - 3073)];
    else v = 0.f;
    out[c] = v;
  }
}

// per-(e,col) batchnorm stats over R rows
__global__ __launch_bounds__(256) void k_bnstats(const float* __restrict__ X,
                                                 float* __restrict__ bm, float* __restrict__ bi, int R) {
  int gid = blockIdx.x * 256 + threadIdx.x;  // NE*DD
  int e = gid >> 10, col = gid & 1023;
  const float* p = X + (size_t)e * R * DD + col;
  float s = 0, s2 = 0;
  for (int r = 0; r < R; ++r) {
    float v = p[(size_t)r * DD];
    s += v;
    s2 += v * v;
  }
  float m = s / R;
  float var = s2 / R - m * m;
  bm[gid] = m;
  bi[gid] = rsqrtf(var + 1e-5f);
}

__global__ __launch_bounds__(256) void k_out2(const float* __restrict__ h2,
                                              const float* __restrict__ bm, const float* __restrict__ bi,
                                              const float* __restrict__ Wo, const float* __restrict__ Wob,
                                              float* __restrict__ out, float* __restrict__ extraf) {
  int e = blockIdx.x >> 3, nn = blockIdx.x & 7;
  int tid = threadIdx.x;
  const float* row = h2 + ((size_t)e * NCK + nn) * DD;
  float l0 = 0, l1 = 0;
  for (int col = tid; col < DD; col += 256) {
    float h = leakyf((row[col] - bm[e * DD + col]) * bi[e * DD + col]);
    l0 += h * Wo[col];
    l1 += h * Wo[DD + col];
  }
  __shared__ float s4[4];
  l0 = blk_sum(l0, s4);
  l1 = blk_sum(l1, s4);
  if (tid == 0) {
    l0 += Wob[0];
    l1 += Wob[1];
    float mx = fmaxf(l0, l1);
    float lse = mx + logf(__expf(l0 - mx) + __expf(l1 - mx));
    out[((size_t)e * NCK + nn) * 2 + 0] = l0 - lse;
    out[((size_t)e * NCK + nn) * 2 + 1] = l1 - lse;
    extraf[e * NCK + nn] = (l1 > l0) ? 1.f : 0.f;
  }
}

// delta3 row builder: [emo | y | dist | emo*y | dis | extra*50 | 0-pad]
__global__ __launch_bounds__(256) void k_delta3(const float* __restrict__ U,
                                                const int* __restrict__ emoI,
                                                const int* __restrict__ cauI,
                                                const float* __restrict__ dis,
                                                const float* __restrict__ extraf,
                                                float* __restrict__ delta3) {
  int e = blockIdx.x >> 7, c = blockIdx.x & 127;
  int tid = threadIdx.x;
  const float* emo = U + (size_t)emoI[e] * DD;
  const float* y = U + (size_t)cauI[c] * DD;
  __shared__ float s4[4];
  float ds = 0;
  for (int d = tid; d < DD; d += 256) {
    float df = emo[d] - y[d];
    ds += df * df;
  }
  float dist = sqrtf(blk_sum(ds, s4));
  float ex = extraf[e * NCK + (c >> 4)];
  float* out = delta3 + ((size_t)e * NCC + c) * K3PAD;
  for (int col = tid; col < K3PAD; col += 256) {
    float v;
    if (col < 1024) v = emo[col];
    else if (col < 2048) v = y[col - 1024];
    else if (col == 2048) v = dist;
    else if (col < 3073) { int d = col - 2049; v = emo[d] * y[d]; }
    else if (col < 3123) v = dis[((size_t)e * NCC + c) * PPP + (col - 3073)];
    else if (col < 3173) v = ex;
    else v = 0.f;
    out[col] = v;
  }
}

__global__ __launch_bounds__(256) void k_p3(const float* __restrict__ h3,
                                            const float* __restrict__ bm, const float* __restrict__ bi,
                                            const float* __restrict__ cw, const float* __restrict__ cb,
                                            float* __restrict__ out) {
  int e = blockIdx.x >> 7, c = blockIdx.x & 127;
  int tid = threadIdx.x;
  const float* row = h3 + ((size_t)e * NCC + c) * DD;
  float l0 = 0, l1 = 0;
  for (int col = tid; col < DD; col += 256) {
    float h = leakyf((row[col] - bm[e * DD + col]) * bi[e * DD + col]);
    l0 += h * cw[col];
    l1 += h * cw[DD + col];
  }
  __shared__ float s4[4];
  l0 = blk_sum(l0, s4);
  l1 = blk_sum(l1, s4);
  if (tid == 0) {
    l0 += cb[0];
    l1 += cb[1];
    float mx = fmaxf(l0, l1);
    float lse = mx + logf(__expf(l0 - mx) + __expf(l1 - mx));
    out[((size_t)e * NCC + c) * 2 + 0] = l0 - lse;
    out[((size_t)e * NCC + c) * 2 + 1] = l1 - lse;
  }
}

__global__ __launch_bounds__(256) void k_L(const int* __restrict__ lab, float* __restrict__ out) {
  int i = blockIdx.x * 256 + threadIdx.x;  // 8192
  int e = i >> 7, c = i & 127;
  int a = lab[e * 3 + 0], b = lab[e * 3 + 1], d = lab[e * 3 + 2];
  out[i] = (a == c || b == c || d == c) ? 1.f : 0.f;
}

extern "C" void kernel_launch(void* const* d_in, const int* in_sizes, int n_in,
                              void* d_out, int out_size, void* d_ws, size_t ws_size,
                              hipStream_t stream) {
  (void)in_sizes; (void)n_in; (void)out_size; (void)ws_size;
  const float* X     = (const float*)d_in[0];
  const float* pos   = (const float*)d_in[1];
  const float* dis   = (const float*)d_in[2];
  const int*   lens  = (const int*)d_in[3];
  const int*   lab3  = (const int*)d_in[4];
  const int*   emoI  = (const int*)d_in[5];
  const int*   cauI  = (const int*)d_in[6];
  const float* Wih_f = (const float*)d_in[7];
  const float* Whh_f = (const float*)d_in[8];
  const float* bih_f = (const float*)d_in[9];
  const float* bhh_f = (const float*)d_in[10];
  const float* Wih_b = (const float*)d_in[11];
  const float* Whh_b = (const float*)d_in[12];
  const float* bih_b = (const float*)d_in[13];
  const float* bhh_b = (const float*)d_in[14];
  const float* s1w   = (const float*)d_in[15];
  const float* s1b   = (const float*)d_in[16];
  const float* s2w   = (const float*)d_in[17];
  const float* W2w   = (const float*)d_in[18];
  const float* W2b   = (const float*)d_in[19];
  const float* Wow   = (const float*)d_in[20];
  const float* Wob   = (const float*)d_in[21];
  const float* W3w   = (const float*)d_in[22];
  const float* W3b   = (const float*)d_in[23];
  const float* clsw  = (const float*)d_in[24];
  const float* clsb  = (const float*)d_in[25];
  float* ws = (float*)d_ws;
  float* out = (float*)d_out;

  // zero-init buffers that are read-before-write
  hipMemsetAsync(ws + F_HSEQ, 0, (size_t)33554432 * sizeof(float), stream);
  hipMemsetAsync(ws + F_HST, 0, (size_t)(524288 + 262144) * sizeof(float), stream);  // Hstate(2buf)+Cstate
  hipMemsetAsync(ws + F_CS, 0, (size_t)2048 * sizeof(float), stream);                // colsum+colsumsq
  hipMemsetAsync(ws + F_ALPHA, 0, (size_t)32768 * sizeof(float), stream);

  // weight transposes (one-time per launch)
  k_transpose<<<dim3(32, 64), 256, 0, stream>>>(Wih_f, ws + F_WCAT, G4, DD, DD);
  k_transpose<<<dim3(16, 64), 256, 0, stream>>>(Whh_f, ws + F_WCAT + (size_t)DD * G4, G4, HH, HH);
  k_transpose<<<dim3(32, 64), 256, 0, stream>>>(Wih_b, ws + F_WCAT + (size_t)KREC * G4, G4, DD, DD);
  k_transpose<<<dim3(16, 64), 256, 0, stream>>>(Whh_b, ws + F_WCAT + (size_t)KREC * G4 + (size_t)DD * G4, G4, HH, HH);
  k_transpose<<<dim3(32, 32), 256, 0, stream>>>(s1w, ws + F_S1WT, DD, DD, DD);
  k_transpose<<<dim3(100, 32), 256, 0, stream>>>(W2w, ws + F_W2T, DD, 3123, K3PAD);
  k_transpose<<<dim3(100, 32), 256, 0, stream>>>(W3w, ws + F_W3T, DD, 3173, K3PAD);
  k_biasc<<<16, 256, 0, stream>>>(bih_f, bhh_f, bih_b, bhh_b, ws + F_BIASC);

  // BiLSTM recurrence (fused input projection), double-buffered h state
  for (int t = 0; t < TT; ++t) {
    const float* Hcur = ws + F_HST + (size_t)(t & 1) * (2 * BB * HH);
    float* Hnext = ws + F_HST + (size_t)((t + 1) & 1) * (2 * BB * HH);
    k_step<<<dim3(16, 16, 2), 256, 0, stream>>>(X, ws + F_WCAT, ws + F_BIASC, lens,
                                                Hcur, Hnext, ws + F_CST, ws + F_HSEQ, t);
  }

  // attention: two-pass z GEMM (stats, then masked-linear attention weights)
  k_gemm<1><<<dim3(512, 16), 256, 0, stream>>>(ws + F_HSEQ, ws + F_S1WT, s1b, nullptr,
                                               NROWS, DD, DD, nullptr, nullptr, nullptr,
                                               ws + F_CS, ws + F_CSQ, nullptr);
  k_bnfinal<<<4, 256, 0, stream>>>(ws + F_CS, ws + F_CSQ, ws + F_BNM, ws + F_BNI, 1.f / NROWS);
  k_gemm<2><<<dim3(512, 16), 256, 0, stream>>>(ws + F_HSEQ, ws + F_S1WT, s1b, nullptr,
                                               NROWS, DD, DD, ws + F_BNM, ws + F_BNI, s2w,
                                               nullptr, nullptr, ws + F_ALPHA);
  k_asum<<<BB, TT, 0, stream>>>(ws + F_ALPHA, lens);
  k_U<<<BB, 256, 0, stream>>>(ws + F_HSEQ, ws + F_ALPHA, ws + F_U);

  // phase 2
  k_p2a<<<NE, 256, 0, stream>>>(ws + F_U, emoI, cauI, ws + F_CHE);
  k_delta2<<<NE * NCK, 256, 0, stream>>>(ws + F_U, emoI, ws + F_CHE, pos, ws + F_D2);
  k_gemm<0><<<dim3(8, 16), 256, 0, stream>>>(ws + F_D2, ws + F_W2T, W2b, ws + F_H2,
                                             NE * NCK, DD, K3PAD, nullptr, nullptr, nullptr,
                                             nullptr, nullptr, nullptr);
  k_bnstats<<<256, 256, 0, stream>>>(ws + F_H2, ws + F_BN2M, ws + F_BN2I, NCK);
  k_out2<<<NE * NCK, 256, 0, stream>>>(ws + F_H2, ws + F_BN2M, ws + F_BN2I, Wow, Wob,
                                       out, ws + F_EXTRA);

  // phase 3 (delta3 reuses Hseq region; Hseq dead after k_U)
  k_delta3<<<NE * NCC, 256, 0, stream>>>(ws + F_U, emoI, cauI, dis, ws + F_EXTRA, ws + F_D3);
  k_gemm<0><<<dim3(128, 16), 256, 0, stream>>>(ws + F_D3, ws + F_W3T, W3b, ws + F_H3,
                                               NE * NCC, DD, K3PAD, nullptr, nullptr, nullptr,
                                               nullptr, nullptr, nullptr);
  k_bnstats<<<256, 256, 0, stream>>>(ws + F_H3, ws + F_BN3M, ws + F_BN3I, NCC);
  k_p3<<<NE * NCC, 256, 0, stream>>>(ws + F_H3, ws + F_BN3M, ws + F_BN3I, clsw, clsb, out + 1024);
  k_L<<<32, 256, 0, stream>>>(lab3, out + 17408);
}

// Round 2
// 18750.381 us; speedup vs baseline: 2.1328x; 2.1328x over previous
//
#include <hip/hip_runtime.h>
#include <math.h>

// ---------------- problem dims ----------------
#define DD    1024
#define TT    128
#define BB    256
#define NE    64
#define NCC   128
#define PPP   50
#define NCK   8
#define HH    512
#define G4    2048     // 4*HH
#define NROWS 32768    // BB*TT
#define K3PAD 3200     // padded K for phase2/3 GEMMs (3123 / 3173 -> 3200)
#define CHUNK 8        // timesteps per XG chunk

// ---------------- workspace layout (float offsets), total 59,548,160 <= 59,875,840 (proven) ----------------
#define F_HSEQ  0ull            // [BB,TT,DD] 33,554,432 ; later D2 (1,638,400 @0), CHE (@26,214,400), D3 (26,214,400 @0)
#define F_XG    33554432ull     // 2 chunk bufs x [2,CHUNK,256,2048] (8,388,608 each)
                                //   after recurrence: W2T(3,276,800) | W3T(3,276,800) | H3(8,388,608)
#define F_WIHT  50331648ull     // [2][1024][2048]
#define F_WHHT  54525952ull     // [2][512][2048]
#define F_BIASC 56623104ull     // [2][2048]
#define F_HST   56627200ull     // 2 buf x [2][256][512]
#define F_CST   57151488ull     // [2][256][512]
#define F_S1WT  57413632ull     // [1024][1024]
#define F_CS    58462208ull
#define F_CSQ   58463232ull
#define F_BNM   58464256ull
#define F_BNI   58465280ull
#define F_ALPHA 58466304ull     // [BB*TT]
#define F_U     58499072ull     // [BB,DD]
#define F_H2    58761216ull     // [64,8,1024]
#define F_BN2M  59285504ull
#define F_BN2I  59351040ull
#define F_EXTRA 59416576ull
#define F_BN3M  59417088ull
#define F_BN3I  59482624ull

#define F_D2    F_HSEQ
#define F_CHE   (F_HSEQ + 26214400ull)
#define F_D3    F_HSEQ
#define F_W2T   F_XG
#define F_W3T   (F_XG + 3276800ull)
#define F_H3    (F_XG + 6553600ull)

__device__ __forceinline__ float leakyf(float x) { return x >= 0.f ? x : 0.01f * x; }
__device__ __forceinline__ float sigmf(float x)  { return 1.f / (1.f + __expf(-x)); }

__device__ __forceinline__ float blk_sum(float v, float* s4) {
  for (int o = 32; o > 0; o >>= 1) v += __shfl_down(v, o);
  __syncthreads();
  if ((threadIdx.x & 63) == 0) s4[threadIdx.x >> 6] = v;
  __syncthreads();
  return s4[0] + s4[1] + s4[2] + s4[3];
}

// ---------------- transpose: dst[k*N+n] = (k<K) ? src[n*K+k] : 0, k in [0,KD) ----------------
__global__ __launch_bounds__(256) void k_transpose(const float* __restrict__ src,
                                                   float* __restrict__ dst,
                                                   int N, int K, int KD) {
  __shared__ float L[32][33];
  int k0 = blockIdx.x * 32;
  int n0 = blockIdx.y * 32;
  int tx = threadIdx.x & 31, ty = threadIdx.x >> 5;
#pragma unroll
  for (int ii = 0; ii < 4; ++ii) {
    int n = n0 + ty + ii * 8, k = k0 + tx;
    float v = 0.f;
    if (n < N && k < K) v = src[(size_t)n * K + k];
    L[ty + ii * 8][tx] = v;
  }
  __syncthreads();
#pragma unroll
  for (int ii = 0; ii < 4; ++ii) {
    int k = k0 + ty + ii * 8, n = n0 + tx;
    if (k < KD && n < N) dst[(size_t)k * N + n] = L[tx][ty + ii * 8];
  }
}

__global__ __launch_bounds__(256) void k_biasc(const float* __restrict__ bf1, const float* __restrict__ bf2,
                                               const float* __restrict__ bb1, const float* __restrict__ bb2,
                                               float* __restrict__ out) {
  int i = blockIdx.x * 256 + threadIdx.x;  // 4096
  if (i < G4) out[i] = bf1[i] + bf2[i];
  else        out[i] = bb1[i - G4] + bb2[i - G4];
}

// ---------------- chunked input projection: XG[dir,tl,b,:] = X[b, r(dir,b,t)] @ WihT[dir] + biasC[dir] ----------------
// grid (32 m-tiles of 64 rows over 2048=CHUNK*256, 32 n-tiles, 2 dirs)
__global__ __launch_bounds__(256) void k_xg(
    const float* __restrict__ X, const float* __restrict__ WihT,
    const float* __restrict__ biasC, const int* __restrict__ lens,
    float* __restrict__ XG, int c) {
  __shared__ float Bs[16][64];   // k-major: read &Bs[k][tx*4] -> bank 4*tx -> 2-way (free)
  const int tid = threadIdx.x;
  const int tx = tid & 15, ty = tid >> 4;
  const int m0 = blockIdx.x * 64, n0 = blockIdx.y * 64;
  const int dir = blockIdx.z;
  const int tl = m0 >> 8;        // 64 | 256 so tl constant per block
  const int t = c * CHUNK + tl;
  float acc[4][4];
#pragma unroll
  for (int i = 0; i < 4; ++i)
#pragma unroll
    for (int j = 0; j < 4; ++j) acc[i][j] = biasC[dir * G4 + n0 + tx * 4 + j];
  const float* Ar[4];
  int brow[4];
#pragma unroll
  for (int i = 0; i < 4; ++i) {
    int b = (m0 + ty * 4 + i) & 255;
    brow[i] = b;
    int len = lens[b];
    int r = (dir == 0) ? t : ((t < len) ? (len - 1 - t) : t);
    Ar[i] = X + ((size_t)b * TT + r) * DD;
  }
  const float* Bt = WihT + (size_t)dir * DD * G4;
  const int skk = tid >> 4, sff = tid & 15;
#pragma unroll 1
  for (int k0 = 0; k0 < DD; k0 += 16) {
    __syncthreads();
    *(float4*)&Bs[skk][sff * 4] = *(const float4*)(Bt + (size_t)(k0 + skk) * G4 + n0 + sff * 4);
    __syncthreads();
#pragma unroll
    for (int kq = 0; kq < 4; ++kq) {
      float4 a0 = *(const float4*)(Ar[0] + k0 + kq * 4);
      float4 a1 = *(const float4*)(Ar[1] + k0 + kq * 4);
      float4 a2 = *(const float4*)(Ar[2] + k0 + kq * 4);
      float4 a3 = *(const float4*)(Ar[3] + k0 + kq * 4);
#pragma unroll
      for (int q = 0; q < 4; ++q) {
        float4 bq = *(const float4*)&Bs[kq * 4 + q][tx * 4];
        float av0 = ((const float*)&a0)[q];
        float av1 = ((const float*)&a1)[q];
        float av2 = ((const float*)&a2)[q];
        float av3 = ((const float*)&a3)[q];
        acc[0][0] += av0 * bq.x; acc[0][1] += av0 * bq.y; acc[0][2] += av0 * bq.z; acc[0][3] += av0 * bq.w;
        acc[1][0] += av1 * bq.x; acc[1][1] += av1 * bq.y; acc[1][2] += av1 * bq.z; acc[1][3] += av1 * bq.w;
        acc[2][0] += av2 * bq.x; acc[2][1] += av2 * bq.y; acc[2][2] += av2 * bq.z; acc[2][3] += av2 * bq.w;
        acc[3][0] += av3 * bq.x; acc[3][1] += av3 * bq.y; acc[3][2] += av3 * bq.z; acc[3][3] += av3 * bq.w;
      }
    }
  }
#pragma unroll
  for (int i = 0; i < 4; ++i) {
    size_t row = (size_t)(dir * CHUNK + tl) * 256 + brow[i];
    float4 o;
    o.x = acc[i][0]; o.y = acc[i][1]; o.z = acc[i][2]; o.w = acc[i][3];
    *(float4*)(XG + row * G4 + n0 + tx * 4) = o;
  }
}

// ---------------- recurrence step: gates = XG[t] + h@WhhT; cell update ----------------
// grid (16 btiles, 16 jtiles, 2 dirs), 256 threads; tile = 16 rows x (4 gates x 32 hcols)
__global__ __launch_bounds__(256, 2) void k_rec(
    const float* __restrict__ XG, const float* __restrict__ WhhT,
    const int* __restrict__ lens,
    const float* __restrict__ Hcur, float* __restrict__ Hnext,
    float* __restrict__ Cst, float* __restrict__ Hseq, int t) {
  __shared__ float Bs[16][128];     // k-major; scalar read Bs[k][cidx] -> 2-way (free)
  __shared__ float gx[2][4][32][8];
  const int tid = threadIdx.x;
  const int b0 = blockIdx.x * 16;
  const int j0 = blockIdx.y * 32;
  const int dir = blockIdx.z;
  const int rg = tid >> 7;
  const int cidx = tid & 127;
  const int g = cidx >> 5;
  const int tc = cidx & 31;
  const int tl = t & (CHUNK - 1);

  float acc[8];
  const float* aH[8];
#pragma unroll
  for (int i = 0; i < 8; ++i) {
    int b = b0 + rg * 8 + i;
    acc[i] = XG[((size_t)(dir * CHUNK + tl) * 256 + b) * G4 + g * HH + j0 + tc];
    aH[i] = Hcur + ((size_t)dir * BB + b) * HH;
  }
  const float* Wd = WhhT + (size_t)dir * HH * G4;

#pragma unroll 1
  for (int k0 = 0; k0 < HH; k0 += 16) {
    __syncthreads();
#pragma unroll
    for (int i = 0; i < 2; ++i) {
      int fidx = tid + i * 256;     // 0..511
      int kk = fidx >> 5;
      int rem = fidx & 31;
      int gg = rem >> 3;
      int ff = rem & 7;
      *(float4*)&Bs[kk][gg * 32 + ff * 4] =
          *(const float4*)(Wd + (size_t)(k0 + kk) * G4 + gg * HH + j0 + ff * 4);
    }
    __syncthreads();
#pragma unroll
    for (int kq = 0; kq < 4; ++kq) {
      float4 a[8];
#pragma unroll
      for (int i = 0; i < 8; ++i) a[i] = *(const float4*)(aH[i] + k0 + kq * 4);
#pragma unroll
      for (int q = 0; q < 4; ++q) {
        float bv = Bs[kq * 4 + q][cidx];
#pragma unroll
        for (int i = 0; i < 8; ++i) acc[i] += ((const float*)&a[i])[q] * bv;
      }
    }
  }
  __syncthreads();
#pragma unroll
  for (int i = 0; i < 8; ++i) gx[rg][g][tc][i] = acc[i];
  __syncthreads();
#pragma unroll 1
  for (int cc = tid; cc < 512; cc += 256) {
    int row = cc >> 5;
    int jj = cc & 31;
    int rg2 = row >> 3, i2 = row & 7;
    float gi = gx[rg2][0][jj][i2];
    float gf = gx[rg2][1][jj][i2];
    float gc = gx[rg2][2][jj][i2];
    float go = gx[rg2][3][jj][i2];
    int b = b0 + row;
    int len = lens[b];
    bool m = (t < len);
    int j = j0 + jj;
    size_t sidx = ((size_t)dir * BB + b) * HH + j;
    float c_old = Cst[sidx];
    float h_old = Hcur[sidx];
    float ig = sigmf(gi);
    float fg = sigmf(gf);
    float cg = tanhf(gc);
    float og = sigmf(go);
    float c_new = fg * c_old + ig * cg;
    float h_new = og * tanhf(c_new);
    if (m) {
      Cst[sidx] = c_new;
      int ro = dir ? (len - 1 - t) : t;
      Hseq[((size_t)b * TT + ro) * DD + dir * HH + j] = h_new;
    }
    Hnext[sidx] = m ? h_new : h_old;
  }
}

// ---------------- generic 64x64 fp32 GEMM, A from global (L1 broadcast), B k-major in LDS ----------------
// MODE 0: C = A@B + bias
// MODE 1: accumulate per-column sum / sumsq of (A@B + bias) into cs/csq (atomic)
// MODE 2: alpha[row] += sum_col leaky((z - bnm)*bni) * s2w[col]  (atomic)
template <int MODE>
__global__ __launch_bounds__(256) void k_gemm(
    const float* __restrict__ A, const float* __restrict__ Bt,
    const float* __restrict__ bias, float* __restrict__ C,
    int M, int N, int K,
    const float* __restrict__ bnm, const float* __restrict__ bni,
    const float* __restrict__ s2w, float* __restrict__ cs,
    float* __restrict__ csq, float* __restrict__ alpha) {
  __shared__ float Bs[16][64];   // k-major
  __shared__ float red[64][17];
  const int tid = threadIdx.x;
  const int tx = tid & 15, ty = tid >> 4;
  const int m0 = blockIdx.x * 64, n0 = blockIdx.y * 64;
  float acc[4][4];
#pragma unroll
  for (int i = 0; i < 4; ++i)
#pragma unroll
    for (int j = 0; j < 4; ++j) acc[i][j] = bias[n0 + tx * 4 + j];
  const float* Ar0 = A + (size_t)(m0 + ty * 4 + 0) * K;
  const float* Ar1 = A + (size_t)(m0 + ty * 4 + 1) * K;
  const float* Ar2 = A + (size_t)(m0 + ty * 4 + 2) * K;
  const float* Ar3 = A + (size_t)(m0 + ty * 4 + 3) * K;
  const int skk = tid >> 4, sff = tid & 15;
#pragma unroll 1
  for (int k0 = 0; k0 < K; k0 += 16) {
    __syncthreads();
    *(float4*)&Bs[skk][sff * 4] = *(const float4*)(Bt + (size_t)(k0 + skk) * N + n0 + sff * 4);
    __syncthreads();
#pragma unroll
    for (int kq = 0; kq < 4; ++kq) {
      float4 a0 = *(const float4*)(Ar0 + k0 + kq * 4);
      float4 a1 = *(const float4*)(Ar1 + k0 + kq * 4);
      float4 a2 = *(const float4*)(Ar2 + k0 + kq * 4);
      float4 a3 = *(const float4*)(Ar3 + k0 + kq * 4);
#pragma unroll
      for (int q = 0; q < 4; ++q) {
        float4 bq = *(const float4*)&Bs[kq * 4 + q][tx * 4];
        float av0 = ((const float*)&a0)[q];
        float av1 = ((const float*)&a1)[q];
        float av2 = ((const float*)&a2)[q];
        float av3 = ((const float*)&a3)[q];
        acc[0][0] += av0 * bq.x; acc[0][1] += av0 * bq.y; acc[0][2] += av0 * bq.z; acc[0][3] += av0 * bq.w;
        acc[1][0] += av1 * bq.x; acc[1][1] += av1 * bq.y; acc[1][2] += av1 * bq.z; acc[1][3] += av1 * bq.w;
        acc[2][0] += av2 * bq.x; acc[2][1] += av2 * bq.y; acc[2][2] += av2 * bq.z; acc[2][3] += av2 * bq.w;
        acc[3][0] += av3 * bq.x; acc[3][1] += av3 * bq.y; acc[3][2] += av3 * bq.z; acc[3][3] += av3 * bq.w;
      }
    }
  }
  if (MODE == 0) {
#pragma unroll
    for (int i = 0; i < 4; ++i) {
      float4 o;
      o.x = acc[i][0]; o.y = acc[i][1]; o.z = acc[i][2]; o.w = acc[i][3];
      *(float4*)(C + (size_t)(m0 + ty * 4 + i) * N + n0 + tx * 4) = o;
    }
  } else if (MODE == 1) {
    float cS[4], cQ[4];
#pragma unroll
    for (int j = 0; j < 4; ++j) {
      cS[j] = acc[0][j] + acc[1][j] + acc[2][j] + acc[3][j];
      cQ[j] = acc[0][j] * acc[0][j] + acc[1][j] * acc[1][j] +
              acc[2][j] * acc[2][j] + acc[3][j] * acc[3][j];
    }
    __syncthreads();
#pragma unroll
    for (int j = 0; j < 4; ++j) red[tx * 4 + j][ty] = cS[j];
    __syncthreads();
    if (tid < 64) {
      float s = 0;
#pragma unroll
      for (int y = 0; y < 16; ++y) s += red[tid][y];
      atomicAdd(&cs[n0 + tid], s);
    }
    __syncthreads();
#pragma unroll
    for (int j = 0; j < 4; ++j) red[tx * 4 + j][ty] = cQ[j];
    __syncthreads();
    if (tid < 64) {
      float s = 0;
#pragma unroll
      for (int y = 0; y < 16; ++y) s += red[tid][y];
      atomicAdd(&csq[n0 + tid], s);
    }
  } else {
    float rs0 = 0, rs1 = 0, rs2 = 0, rs3 = 0;
#pragma unroll
    for (int j = 0; j < 4; ++j) {
      int col = n0 + tx * 4 + j;
      float mc = bnm[col], ic = bni[col], wc = s2w[col];
      rs0 += leakyf((acc[0][j] - mc) * ic) * wc;
      rs1 += leakyf((acc[1][j] - mc) * ic) * wc;
      rs2 += leakyf((acc[2][j] - mc) * ic) * wc;
      rs3 += leakyf((acc[3][j] - mc) * ic) * wc;
    }
    __syncthreads();
    red[ty * 4 + 0][tx] = rs0;
    red[ty * 4 + 1][tx] = rs1;
    red[ty * 4 + 2][tx] = rs2;
    red[ty * 4 + 3][tx] = rs3;
    __syncthreads();
    if (tid < 64) {
      float s = 0;
#pragma unroll
      for (int x = 0; x < 16; ++x) s += red[tid][x];
      atomicAdd(&alpha[m0 + tid], s);
    }
  }
}

__global__ __launch_bounds__(256) void k_bnfinal(const float* __restrict__ cs, const float* __restrict__ csq,
                                                 float* __restrict__ bnm, float* __restrict__ bni, float invN) {
  int i = blockIdx.x * 256 + threadIdx.x;
  if (i < DD) {
    float m = cs[i] * invN;
    float v = csq[i] * invN - m * m;
    bnm[i] = m;
    bni[i] = rsqrtf(v + 1e-5f);
  }
}

__global__ __launch_bounds__(128) void k_asum(float* __restrict__ alpha, const int* __restrict__ lens) {
  int b = blockIdx.x;
  int t = threadIdx.x;
  int len = lens[b];
  float v = (t < len) ? alpha[b * TT + t] : 0.f;
  float s = v;
  for (int o = 32; o > 0; o >>= 1) s += __shfl_down(s, o);
  __shared__ float sw[2];
  if ((t & 63) == 0) sw[t >> 6] = s;
  __syncthreads();
  float S = sw[0] + sw[1] + 1e-9f;
  alpha[b * TT + t] = v / S;
}

__global__ __launch_bounds__(256) void k_U(const float* __restrict__ Hseq,
                                           const float* __restrict__ alpha,
                                           float* __restrict__ U) {
  int b = blockIdx.x;
  int tid = threadIdx.x;
  __shared__ float al[TT];
  if (tid < TT) al[tid] = alpha[b * TT + tid];
  __syncthreads();
  float4 s = make_float4(0.f, 0.f, 0.f, 0.f);
  const float* Hb = Hseq + (size_t)b * TT * DD + tid * 4;
#pragma unroll 4
  for (int t = 0; t < TT; ++t) {
    float a = al[t];
    float4 h = *(const float4*)(Hb + (size_t)t * DD);
    s.x += a * h.x; s.y += a * h.y; s.z += a * h.z; s.w += a * h.w;
  }
  *(float4*)(U + (size_t)b * DD + tid * 4) = s;
}

__global__ __launch_bounds__(256) void k_p2a(const float* __restrict__ U,
                                             const int* __restrict__ emoI,
                                             const int* __restrict__ cauI,
                                             float* __restrict__ chunkEmb) {
  int e = blockIdx.x;
  int tid = threadIdx.x;
  __shared__ float emoS[DD];
  __shared__ float sc[NCK][16];
  const float* Ue = U + (size_t)emoI[e] * DD;
  for (int i = tid; i < DD; i += 256) emoS[i] = Ue[i];
  __syncthreads();
  int w = tid >> 6, lane = tid & 63;
  for (int p = w; p < 128; p += 4) {
    const float* y = U + (size_t)cauI[p] * DD;
    float s = 0;
    for (int d = lane; d < DD; d += 64) s += emoS[d] * y[d];
    for (int o = 32; o > 0; o >>= 1) s += __shfl_down(s, o);
    if (lane == 0) sc[p >> 4][p & 15] = s;
  }
  __syncthreads();
  if (tid < NCK) {
    float mx = -1e30f;
    for (int c = 0; c < 16; ++c) mx = fmaxf(mx, sc[tid][c]);
    float sum = 0;
    for (int c = 0; c < 16; ++c) {
      float ev = __expf(sc[tid][c] - mx);
      sc[tid][c] = ev;
      sum += ev;
    }
    float inv = 1.f / sum;
    for (int c = 0; c < 16; ++c) sc[tid][c] *= inv;
  }
  __syncthreads();
  int d = tid * 4;
  for (int nn = 0; nn < NCK; ++nn) {
    float4 s = make_float4(0.f, 0.f, 0.f, 0.f);
    for (int c = 0; c < 16; ++c) {
      float wc = sc[nn][c];
      float4 y = *(const float4*)(U + (size_t)cauI[nn * 16 + c] * DD + d);
      s.x += wc * y.x; s.y += wc * y.y; s.z += wc * y.z; s.w += wc * y.w;
    }
    *(float4*)(chunkEmb + ((size_t)e * NCK + nn) * DD + d) = s;
  }
}

__global__ __launch_bounds__(256) void k_delta2(const float* __restrict__ U,
                                                const int* __restrict__ emoI,
                                                const float* __restrict__ chunkEmb,
                                                const float* __restrict__ pos,
                                                float* __restrict__ delta2) {
  int e = blockIdx.x >> 3, nn = blockIdx.x & 7;
  int tid = threadIdx.x;
  const float* emo = U + (size_t)emoI[e] * DD;
  const float* y = chunkEmb + ((size_t)e * NCK + nn) * DD;
  __shared__ float s4[4];
  float ds = 0;
  for (int d = tid; d < DD; d += 256) {
    float df = emo[d] - y[d];
    ds += df * df;
  }
  float dist = sqrtf(blk_sum(ds, s4));
  float* out = delta2 + ((size_t)e * NCK + nn) * K3PAD;
  for (int c = tid; c < K3PAD; c += 256) {
    float v;
    if (c < 1024) v = emo[c];
    else if (c < 2048) v = y[c - 1024];
    else if (c == 2048) v = dist;
    else if (c < 3073) { int d = c - 2049; v = emo[d] * y[d]; }
    else if (c < 3123) v = pos[((size_t)e * NCK + nn) * PPP + (c - 3073)];
    else v = 0.f;
    out[c] = v;
  }
}

__global__ __launch_bounds__(256) void k_bnstats(const float* __restrict__ X,
                                                 float* __restrict__ bm, float* __restrict__ bi, int R) {
  int gid = blockIdx.x * 256 + threadIdx.x;  // NE*DD
  int e = gid >> 10, col = gid & 1023;
  const float* p = X + (size_t)e * R * DD + col;
  float s = 0, s2 = 0;
  for (int r = 0; r < R; ++r) {
    float v = p[(size_t)r * DD];
    s += v;
    s2 += v * v;
  }
  float m = s / R;
  float var = s2 / R - m * m;
  bm[gid] = m;
  bi[gid] = rsqrtf(var + 1e-5f);
}

__global__ __launch_bounds__(256) void k_out2(const float* __restrict__ h2,
                                              const float* __restrict__ bm, const float* __restrict__ bi,
                                              const float* __restrict__ Wo, const float* __restrict__ Wob,
                                              float* __restrict__ out, float* __restrict__ extraf) {
  int e = blockIdx.x >> 3, nn = blockIdx.x & 7;
  int tid = threadIdx.x;
  const float* row = h2 + ((size_t)e * NCK + nn) * DD;
  float l0 = 0, l1 = 0;
  for (int col = tid; col < DD; col += 256) {
    float h = leakyf((row[col] - bm[e * DD + col]) * bi[e * DD + col]);
    l0 += h * Wo[col];
    l1 += h * Wo[DD + col];
  }
  __shared__ float s4[4];
  l0 = blk_sum(l0, s4);
  l1 = blk_sum(l1, s4);
  if (tid == 0) {
    l0 += Wob[0];
    l1 += Wob[1];
    float mx = fmaxf(l0, l1);
    float lse = mx + logf(__expf(l0 - mx) + __expf(l1 - mx));
    out[((size_t)e * NCK + nn) * 2 + 0] = l0 - lse;
    out[((size_t)e * NCK + nn) * 2 + 1] = l1 - lse;
    extraf[e * NCK + nn] = (l1 > l0) ? 1.f : 0.f;
  }
}

__global__ __launch_bounds__(256) void k_delta3(const float* __restrict__ U,
                                                const int* __restrict__ emoI,
                                                const int* __restrict__ cauI,
                                                const float* __restrict__ dis,
                                                const float* __restrict__ extraf,
                                                float* __restrict__ delta3) {
  int e = blockIdx.x >> 7, c = blockIdx.x & 127;
  int tid = threadIdx.x;
  const float* emo = U + (size_t)emoI[e] * DD;
  const float* y = U + (size_t)cauI[c] * DD;
  __shared__ float s4[4];
  float ds = 0;
  for (int d = tid; d < DD; d += 256) {
    float df = emo[d] - y[d];
    ds += df * df;
  }
  float dist = sqrtf(blk_sum(ds, s4));
  float ex = extraf[e * NCK + (c >> 4)];
  float* out = delta3 + ((size_t)e * NCC + c) * K3PAD;
  for (int col = tid; col < K3PAD; col += 256) {
    float v;
    if (col < 1024) v = emo[col];
    else if (col < 2048) v = y[col - 1024];
    else if (col == 2048) v = dist;
    else if (col < 3073) { int d = col - 2049; v = emo[d] * y[d]; }
    else if (col < 3123) v = dis[((size_t)e * NCC + c) * PPP + (col - 3073)];
    else if (col < 3173) v = ex;
    else v = 0.f;
    out[col] = v;
  }
}

__global__ __launch_bounds__(256) void k_p3(const float* __restrict__ h3,
                                            const float* __restrict__ bm, const float* __restrict__ bi,
                                            const float* __restrict__ cw, const float* __restrict__ cb,
                                            float* __restrict__ out) {
  int e = blockIdx.x >> 7, c = blockIdx.x & 127;
  int tid = threadIdx.x;
  const float* row = h3 + ((size_t)e * NCC + c) * DD;
  float l0 = 0, l1 = 0;
  for (int col = tid; col < DD; col += 256) {
    float h = leakyf((row[col] - bm[e * DD + col]) * bi[e * DD + col]);
    l0 += h * cw[col];
    l1 += h * cw[DD + col];
  }
  __shared__ float s4[4];
  l0 = blk_sum(l0, s4);
  l1 = blk_sum(l1, s4);
  if (tid == 0) {
    l0 += cb[0];
    l1 += cb[1];
    float mx = fmaxf(l0, l1);
    float lse = mx + logf(__expf(l0 - mx) + __expf(l1 - mx));
    out[((size_t)e * NCC + c) * 2 + 0] = l0 - lse;
    out[((size_t)e * NCC + c) * 2 + 1] = l1 - lse;
  }
}

__global__ __launch_bounds__(256) void k_L(const int* __restrict__ lab, float* __restrict__ out) {
  int i = blockIdx.x * 256 + threadIdx.x;  // 8192
  int e = i >> 7, c = i & 127;
  int a = lab[e * 3 + 0], b = lab[e * 3 + 1], d = lab[e * 3 + 2];
  out[i] = (a == c || b == c || d == c) ? 1.f : 0.f;
}

extern "C" void kernel_launch(void* const* d_in, const int* in_sizes, int n_in,
                              void* d_out, int out_size, void* d_ws, size_t ws_size,
                              hipStream_t stream) {
  (void)in_sizes; (void)n_in; (void)out_size; (void)ws_size;
  const float* X     = (const float*)d_in[0];
  const float* pos   = (const float*)d_in[1];
  const float* dis   = (const float*)d_in[2];
  const int*   lens  = (const int*)d_in[3];
  const int*   lab3  = (const int*)d_in[4];
  const int*   emoI  = (const int*)d_in[5];
  const int*   cauI  = (const int*)d_in[6];
  const float* Wih_f = (const float*)d_in[7];
  const float* Whh_f = (const float*)d_in[8];
  const float* bih_f = (const float*)d_in[9];
  const float* bhh_f = (const float*)d_in[10];
  const float* Wih_b = (const float*)d_in[11];
  const float* Whh_b = (const float*)d_in[12];
  const float* bih_b = (const float*)d_in[13];
  const float* bhh_b = (const float*)d_in[14];
  const float* s1w   = (const float*)d_in[15];
  const float* s1b   = (const float*)d_in[16];
  const float* s2w   = (const float*)d_in[17];
  const float* W2w   = (const float*)d_in[18];
  const float* W2b   = (const float*)d_in[19];
  const float* Wow   = (const float*)d_in[20];
  const float* Wob   = (const float*)d_in[21];
  const float* W3w   = (const float*)d_in[22];
  const float* W3b   = (const float*)d_in[23];
  const float* clsw  = (const float*)d_in[24];
  const float* clsb  = (const float*)d_in[25];
  float* ws = (float*)d_ws;
  float* out = (float*)d_out;

  // zero-init buffers that are read-before-write (padded Hseq rows MUST be exactly 0 for BN stats)
  hipMemsetAsync(ws + F_HSEQ, 0, (size_t)33554432 * sizeof(float), stream);
  hipMemsetAsync(ws + F_HST, 0, (size_t)(524288 + 262144) * sizeof(float), stream);
  hipMemsetAsync(ws + F_CS, 0, (size_t)2048 * sizeof(float), stream);
  hipMemsetAsync(ws + F_ALPHA, 0, (size_t)32768 * sizeof(float), stream);

  // weight transposes
  k_transpose<<<dim3(32, 64), 256, 0, stream>>>(Wih_f, ws + F_WIHT, G4, DD, DD);
  k_transpose<<<dim3(32, 64), 256, 0, stream>>>(Wih_b, ws + F_WIHT + (size_t)DD * G4, G4, DD, DD);
  k_transpose<<<dim3(16, 64), 256, 0, stream>>>(Whh_f, ws + F_WHHT, G4, HH, HH);
  k_transpose<<<dim3(16, 64), 256, 0, stream>>>(Whh_b, ws + F_WHHT + (size_t)HH * G4, G4, HH, HH);
  k_transpose<<<dim3(32, 32), 256, 0, stream>>>(s1w, ws + F_S1WT, DD, DD, DD);
  k_biasc<<<16, 256, 0, stream>>>(bih_f, bhh_f, bih_b, bhh_b, ws + F_BIASC);

  // BiLSTM: chunked input-projection GEMMs interleaved with h@Whh recurrence steps
  for (int c = 0; c < TT / CHUNK; ++c) {
    float* XGbuf = ws + F_XG + (size_t)(c & 1) * (2 * CHUNK * 256 * G4);
    k_xg<<<dim3(32, 32, 2), 256, 0, stream>>>(X, ws + F_WIHT, ws + F_BIASC, lens, XGbuf, c);
    for (int tt = 0; tt < CHUNK; ++tt) {
      int t = c * CHUNK + tt;
      const float* Hcur = ws + F_HST + (size_t)(t & 1) * (2 * BB * HH);
      float* Hnext = ws + F_HST + (size_t)((t + 1) & 1) * (2 * BB * HH);
      k_rec<<<dim3(16, 16, 2), 256, 0, stream>>>(XGbuf, ws + F_WHHT, lens,
                                                 Hcur, Hnext, ws + F_CST, ws + F_HSEQ, t);
    }
  }

  // attention: two-pass z GEMM
  k_gemm<1><<<dim3(512, 16), 256, 0, stream>>>(ws + F_HSEQ, ws + F_S1WT, s1b, nullptr,
                                               NROWS, DD, DD, nullptr, nullptr, nullptr,
                                               ws + F_CS, ws + F_CSQ, nullptr);
  k_bnfinal<<<4, 256, 0, stream>>>(ws + F_CS, ws + F_CSQ, ws + F_BNM, ws + F_BNI, 1.f / NROWS);
  k_gemm<2><<<dim3(512, 16), 256, 0, stream>>>(ws + F_HSEQ, ws + F_S1WT, s1b, nullptr,
                                               NROWS, DD, DD, ws + F_BNM, ws + F_BNI, s2w,
                                               nullptr, nullptr, ws + F_ALPHA);
  k_asum<<<BB, TT, 0, stream>>>(ws + F_ALPHA, lens);
  k_U<<<BB, 256, 0, stream>>>(ws + F_HSEQ, ws + F_ALPHA, ws + F_U);

  // phase-2/3 weight transposes (into dead XG region — must be after last k_rec)
  k_transpose<<<dim3(100, 32), 256, 0, stream>>>(W2w, ws + F_W2T, DD, 3123, K3PAD);
  k_transpose<<<dim3(100, 32), 256, 0, stream>>>(W3w, ws + F_W3T, DD, 3173, K3PAD);

  // phase 2 (D2/CHE live in dead Hseq region)
  k_p2a<<<NE, 256, 0, stream>>>(ws + F_U, emoI, cauI, ws + F_CHE);
  k_delta2<<<NE * NCK, 256, 0, stream>>>(ws + F_U, emoI, ws + F_CHE, pos, ws + F_D2);
  k_gemm<0><<<dim3(8, 16), 256, 0, stream>>>(ws + F_D2, ws + F_W2T, W2b, ws + F_H2,
                                             NE * NCK, DD, K3PAD, nullptr, nullptr, nullptr,
                                             nullptr, nullptr, nullptr);
  k_bnstats<<<256, 256, 0, stream>>>(ws + F_H2, ws + F_BN2M, ws + F_BN2I, NCK);
  k_out2<<<NE * NCK, 256, 0, stream>>>(ws + F_H2, ws + F_BN2M, ws + F_BN2I, Wow, Wob,
                                       out, ws + F_EXTRA);

  // phase 3 (D3 overlays Hseq/D2; H3 in dead XG region after W2T/W3T)
  k_delta3<<<NE * NCC, 256, 0, stream>>>(ws + F_U, emoI, cauI, dis, ws + F_EXTRA, ws + F_D3);
  k_gemm<0><<<dim3(128, 16), 256, 0, stream>>>(ws + F_D3, ws + F_W3T, W3b, ws + F_H3,
                                               NE * NCC, DD, K3PAD, nullptr, nullptr, nullptr,
                                               nullptr, nullptr, nullptr);
  k_bnstats<<<256, 256, 0, stream>>>(ws + F_H3, ws + F_BN3M, ws + F_BN3I, NCC);
  k_p3<<<NE * NCC, 256, 0, stream>>>(ws + F_H3, ws + F_BN3M, ws + F_BN3I, clsw, clsb, out + 1024);
  k_L<<<32, 256, 0, stream>>>(lab3, out + 17408);
}

// Round 3
// 6164.692 us; speedup vs baseline: 6.4871x; 3.0416x over previous
//
#include <hip/hip_runtime.h>
#include <math.h>

// ---------------- problem dims ----------------
#define DD    1024
#define TT    128
#define BB    256
#define NE    64
#define NCC   128
#define PPP   50
#define NCK   8
#define HH    512
#define G4    2048     // 4*HH
#define NROWS 32768    // BB*TT
#define K3PAD 3200     // padded K for phase2/3 GEMMs (3123 / 3173 -> 3200)
#define CHUNK 8        // timesteps per XG chunk

// ---------------- workspace layout (float offsets), total 58,762,240 floats = 235 MB ----------------
#define F_HSEQ  0ull            // [BB,TT,DD] fp32 33,554,432 ; overlaid later: D2, CHE, D3
#define F_XG    33554432ull     // [2][CHUNK][256][2048] fp32 8,388,608 ; later H3
#define F_WIH   41943040ull     // bf16 hi[2][2048][1024] + lo  (4,194,304 float-slots)
#define F_WHH   46137344ull     // bf16 hi[2][2048][512] + lo   (2,097,152)
#define F_S1    48234496ull     // bf16 hi[1024][1024] + lo     (1,048,576)
#define F_W2    49283072ull     // bf16 hi[1024][3200] + lo     (3,276,800)
#define F_W3    52559872ull     // bf16 hi[1024][3200] + lo     (3,276,800)
#define F_GW    55836672ull     // [2][256][2048] fp32 1,048,576
#define F_BIASC 56885248ull     // [2][2048]
#define F_HST   56889344ull     // 2 buf x [2][256][512] = 524,288
#define F_CST   57413632ull     // [2][256][512] = 262,144
#define F_CS    57675776ull
#define F_CSQ   57676800ull
#define F_BNM   57677824ull
#define F_BNI   57678848ull
#define F_ALPHA 57679872ull     // [BB*TT]
#define F_U     57712640ull     // [BB,DD] 262,144
#define F_H2    57974784ull     // [64,8,1024] 524,288
#define F_BN2M  58499072ull
#define F_BN2I  58564608ull
#define F_EXTRA 58630144ull
#define F_BN3M  58631168ull
#define F_BN3I  58696704ull

#define F_D2    F_HSEQ
#define F_CHE   (F_HSEQ + 26214400ull)
#define F_D3    F_HSEQ
#define F_H3    F_XG

typedef short s8v __attribute__((ext_vector_type(8)));
typedef float f4v __attribute__((ext_vector_type(4)));

__device__ __forceinline__ float leakyf(float x) { return x >= 0.f ? x : 0.01f * x; }
__device__ __forceinline__ float sigmf(float x)  { return 1.f / (1.f + __expf(-x)); }

__device__ __forceinline__ float blk_sum(float v, float* s4) {
  for (int o = 32; o > 0; o >>= 1) v += __shfl_down(v, o);
  __syncthreads();
  if ((threadIdx.x & 63) == 0) s4[threadIdx.x >> 6] = v;
  __syncthreads();
  return s4[0] + s4[1] + s4[2] + s4[3];
}

// pack 2 fp32 -> (hi bf16 pair, lo bf16 pair); hi = truncation, lo = exact residual truncated
__device__ __forceinline__ void cvt2(float x0, float x1, unsigned& hi, unsigned& lo) {
  unsigned b0 = __float_as_uint(x0), b1 = __float_as_uint(x1);
  hi = (b0 >> 16) | (b1 & 0xffff0000u);
  float h0 = __uint_as_float(b0 & 0xffff0000u);
  float h1 = __uint_as_float(b1 & 0xffff0000u);
  unsigned l0 = __float_as_uint(x0 - h0);
  unsigned l1 = __float_as_uint(x1 - h1);
  lo = (l0 >> 16) | (l1 & 0xffff0000u);
}

// weight convert: src fp32 [N][Ks] row-major -> hi/lo bf16 [N][Kd] (zero-padded)
__global__ __launch_bounds__(256) void k_cvt(const float* __restrict__ src,
                                             unsigned short* __restrict__ hi,
                                             unsigned short* __restrict__ lo,
                                             int Ks, int Kd) {
  int n = blockIdx.x;
  for (int k = threadIdx.x; k < Kd; k += 256) {
    float v = (k < Ks) ? src[(size_t)n * Ks + k] : 0.f;
    unsigned b = __float_as_uint(v);
    float h = __uint_as_float(b & 0xffff0000u);
    hi[(size_t)n * Kd + k] = (unsigned short)(b >> 16);
    lo[(size_t)n * Kd + k] = (unsigned short)(__float_as_uint(v - h) >> 16);
  }
}

__global__ __launch_bounds__(256) void k_biasc(const float* __restrict__ bf1, const float* __restrict__ bf2,
                                               const float* __restrict__ bb1, const float* __restrict__ bb2,
                                               float* __restrict__ out) {
  int i = blockIdx.x * 256 + threadIdx.x;  // 4096
  if (i < G4) out[i] = bf1[i] + bf2[i];
  else        out[i] = bb1[i - G4] + bb2[i - G4];
}

// ---------------- MFMA GEMM, 128x128 tile, split-bf16 3-term (fp32-accurate) ----------------
// A fp32 [M,K] (rows gathered for XG), B bf16 hi/lo n-major [N][K].
// MODE 0 STORE: C = A@B + bias          (p2/p3 GEMMs)
// MODE 1 STATS: atomic col sum/sumsq of (A@B + bias)        (z pass 1)
// MODE 2 ALPHA: atomic row sum of leaky((z-bnm)*bni)*s2w    (z pass 2)
// MODE 3 XG:    gathered A rows from X via lens; dir = blockIdx.z
// MODE 4 REC:   A/B/C offset by dir = blockIdx.z; no bias
template <int MODE>
__global__ __launch_bounds__(256, 2) void k_mf(
    const float* __restrict__ A, const unsigned short* __restrict__ Bhi,
    const unsigned short* __restrict__ Blo, const float* __restrict__ bias,
    float* __restrict__ C, int M, int N, int K,
    const int* __restrict__ lens, int c,
    const float* __restrict__ bnm, const float* __restrict__ bni,
    const float* __restrict__ s2w, float* __restrict__ cs,
    float* __restrict__ csq, float* __restrict__ alpha) {
  __shared__ unsigned short Ah[128][40];
  __shared__ unsigned short Al[128][40];
  __shared__ unsigned short Bh[128][40];
  __shared__ unsigned short Bl[128][40];
  const int tid = threadIdx.x;
  const int m0 = blockIdx.x * 128;
  const int n0 = blockIdx.y * 128;
  const int dir = (MODE == 3 || MODE == 4) ? blockIdx.z : 0;

  // staging assignment: thread stages row sr, k-half sh (16 elements)
  const int sr = tid >> 1;
  const int sh = tid & 1;
  const float* arow;
  if (MODE == 3) {
    int tl = m0 >> 8;                       // 128 | m0, so tl constant per block
    int b = (m0 & 255) + sr;
    int t = c * CHUNK + tl;
    int len = lens[b];
    int r = (dir == 0) ? t : ((t < len) ? (len - 1 - t) : t);
    arow = A + ((size_t)b * TT + r) * DD;
  } else if (MODE == 4) {
    arow = A + ((size_t)dir * M + m0 + sr) * K;
  } else {
    arow = A + (size_t)(m0 + sr) * K;
  }
  const unsigned short* bhrow = Bhi + ((size_t)dir * N + n0 + sr) * K;
  const unsigned short* blrow = Blo + ((size_t)dir * N + n0 + sr) * K;

  const int wave = tid >> 6, lane = tid & 63;
  const int wm = wave & 1, wn = wave >> 1;
  const int quad = lane >> 4, l15 = lane & 15;

  f4v acc[4][4];
#pragma unroll
  for (int i = 0; i < 4; ++i)
#pragma unroll
    for (int j = 0; j < 4; ++j) acc[i][j] = (f4v){0.f, 0.f, 0.f, 0.f};

#pragma unroll 1
  for (int k0 = 0; k0 < K; k0 += 32) {
    __syncthreads();
    {
      const float4* pa = (const float4*)(arow + k0 + sh * 16);
      float4 v0 = pa[0], v1 = pa[1], v2 = pa[2], v3 = pa[3];
      unsigned h[8], l[8];
      cvt2(v0.x, v0.y, h[0], l[0]); cvt2(v0.z, v0.w, h[1], l[1]);
      cvt2(v1.x, v1.y, h[2], l[2]); cvt2(v1.z, v1.w, h[3], l[3]);
      cvt2(v2.x, v2.y, h[4], l[4]); cvt2(v2.z, v2.w, h[5], l[5]);
      cvt2(v3.x, v3.y, h[6], l[6]); cvt2(v3.z, v3.w, h[7], l[7]);
      uint4* dh = (uint4*)&Ah[sr][sh * 16];
      dh[0] = make_uint4(h[0], h[1], h[2], h[3]);
      dh[1] = make_uint4(h[4], h[5], h[6], h[7]);
      uint4* dl = (uint4*)&Al[sr][sh * 16];
      dl[0] = make_uint4(l[0], l[1], l[2], l[3]);
      dl[1] = make_uint4(l[4], l[5], l[6], l[7]);
      const uint4* pbh = (const uint4*)(bhrow + k0 + sh * 16);
      uint4* dbh = (uint4*)&Bh[sr][sh * 16];
      dbh[0] = pbh[0]; dbh[1] = pbh[1];
      const uint4* pbl = (const uint4*)(blrow + k0 + sh * 16);
      uint4* dbl = (uint4*)&Bl[sr][sh * 16];
      dbl[0] = pbl[0]; dbl[1] = pbl[1];
    }
    __syncthreads();
    s8v ah[4], al[4], bh[4], bl[4];
#pragma unroll
    for (int mi = 0; mi < 4; ++mi) {
      ah[mi] = *(const s8v*)&Ah[wm * 64 + mi * 16 + l15][quad * 8];
      al[mi] = *(const s8v*)&Al[wm * 64 + mi * 16 + l15][quad * 8];
    }
#pragma unroll
    for (int ni = 0; ni < 4; ++ni) {
      bh[ni] = *(const s8v*)&Bh[wn * 64 + ni * 16 + l15][quad * 8];
      bl[ni] = *(const s8v*)&Bl[wn * 64 + ni * 16 + l15][quad * 8];
    }
#pragma unroll
    for (int mi = 0; mi < 4; ++mi)
#pragma unroll
      for (int ni = 0; ni < 4; ++ni) {
        acc[mi][ni] = __builtin_amdgcn_mfma_f32_16x16x32_bf16(ah[mi], bh[ni], acc[mi][ni], 0, 0, 0);
        acc[mi][ni] = __builtin_amdgcn_mfma_f32_16x16x32_bf16(al[mi], bh[ni], acc[mi][ni], 0, 0, 0);
        acc[mi][ni] = __builtin_amdgcn_mfma_f32_16x16x32_bf16(ah[mi], bl[ni], acc[mi][ni], 0, 0, 0);
      }
  }

  // epilogue; C/D layout: col = l15, row = quad*4 + reg  (within 16x16 frag)
  const int rb = wm * 64;
  if (MODE == 0 || MODE == 3 || MODE == 4) {
    float* Cb;
    const float* bp = bias;
    if (MODE == 3) {
      int tl = m0 >> 8;
      Cb = C + (((size_t)dir * CHUNK + tl) * 256 + (m0 & 255)) * (size_t)N;
      bp = bias + (size_t)dir * N;
    } else if (MODE == 4) {
      Cb = C + ((size_t)dir * M + m0) * (size_t)N;
    } else {
      Cb = C + (size_t)m0 * N;
    }
#pragma unroll
    for (int mi = 0; mi < 4; ++mi)
#pragma unroll
      for (int ni = 0; ni < 4; ++ni) {
        int col = n0 + wn * 64 + ni * 16 + l15;
        float bv = (MODE == 4) ? 0.f : bp[col];
#pragma unroll
        for (int r = 0; r < 4; ++r) {
          int row = rb + mi * 16 + quad * 4 + r;
          Cb[(size_t)row * N + col] = acc[mi][ni][r] + bv;
        }
      }
  } else if (MODE == 1) {
#pragma unroll
    for (int ni = 0; ni < 4; ++ni) {
      int col = n0 + wn * 64 + ni * 16 + l15;
      float bv = bias[col];
      float s = 0.f, q = 0.f;
#pragma unroll
      for (int mi = 0; mi < 4; ++mi)
#pragma unroll
        for (int r = 0; r < 4; ++r) {
          float z = acc[mi][ni][r] + bv;
          s += z;
          q += z * z;
        }
      s += __shfl_xor(s, 16); s += __shfl_xor(s, 32);
      q += __shfl_xor(q, 16); q += __shfl_xor(q, 32);
      if (quad == 0) {
        atomicAdd(&cs[col], s);
        atomicAdd(&csq[col], q);
      }
    }
  } else {  // MODE 2
#pragma unroll
    for (int mi = 0; mi < 4; ++mi) {
      float rv[4] = {0.f, 0.f, 0.f, 0.f};
#pragma unroll
      for (int ni = 0; ni < 4; ++ni) {
        int col = n0 + wn * 64 + ni * 16 + l15;
        float bv = bias[col], mc = bnm[col], ic = bni[col], wc = s2w[col];
#pragma unroll
        for (int r = 0; r < 4; ++r) {
          float z = acc[mi][ni][r] + bv;
          rv[r] += leakyf((z - mc) * ic) * wc;
        }
      }
#pragma unroll
      for (int r = 0; r < 4; ++r) {
        float v = rv[r];
        v += __shfl_xor(v, 1); v += __shfl_xor(v, 2);
        v += __shfl_xor(v, 4); v += __shfl_xor(v, 8);
        if (l15 == 0) atomicAdd(&alpha[m0 + rb + mi * 16 + quad * 4 + r], v);
      }
    }
  }
}

// ---------------- LSTM cell update: gates = XG[t] + GW; update c,h; write Hseq ----------------
__global__ __launch_bounds__(256) void k_cell(const float* __restrict__ XG, const float* __restrict__ GW,
                                              const int* __restrict__ lens,
                                              const float* __restrict__ Hcur, float* __restrict__ Hnext,
                                              float* __restrict__ Cst, float* __restrict__ Hseq, int t) {
  int id = blockIdx.x * 256 + threadIdx.x;  // 65536 threads, 4 cols each
  int dir = id >> 15;
  int rem = id & 32767;
  int b = rem >> 7;
  int j = (rem & 127) << 2;
  int tl = t & (CHUNK - 1);
  const float* xg = XG + (((size_t)dir * CHUNK + tl) * 256 + b) * G4;
  const float* gw = GW + ((size_t)dir * 256 + b) * G4;
  float4 zi = *(const float4*)(xg + j);
  float4 zf = *(const float4*)(xg + HH + j);
  float4 zg = *(const float4*)(xg + 2 * HH + j);
  float4 zo = *(const float4*)(xg + 3 * HH + j);
  float4 wi = *(const float4*)(gw + j);
  float4 wf = *(const float4*)(gw + HH + j);
  float4 wg = *(const float4*)(gw + 2 * HH + j);
  float4 wo = *(const float4*)(gw + 3 * HH + j);
  int len = lens[b];
  bool m = t < len;
  size_t sidx = ((size_t)dir * BB + b) * HH + j;
  float4 cold = *(const float4*)(Cst + sidx);
  float4 hold = *(const float4*)(Hcur + sidx);
  float4 cnew, hnew;
#pragma unroll
  for (int cc = 0; cc < 4; ++cc) {
    float gi = (&zi.x)[cc] + (&wi.x)[cc];
    float gf = (&zf.x)[cc] + (&wf.x)[cc];
    float gg = (&zg.x)[cc] + (&wg.x)[cc];
    float go = (&zo.x)[cc] + (&wo.x)[cc];
    float cn = sigmf(gf) * (&cold.x)[cc] + sigmf(gi) * tanhf(gg);
    (&cnew.x)[cc] = cn;
    (&hnew.x)[cc] = sigmf(go) * tanhf(cn);
  }
  if (m) {
    *(float4*)(Cst + sidx) = cnew;
    int ro = dir ? (len - 1 - t) : t;
    *(float4*)(Hseq + ((size_t)b * TT + ro) * DD + dir * HH + j) = hnew;
    *(float4*)(Hnext + sidx) = hnew;
  } else {
    *(float4*)(Hnext + sidx) = hold;
  }
}

__global__ __launch_bounds__(256) void k_bnfinal(const float* __restrict__ cs, const float* __restrict__ csq,
                                                 float* __restrict__ bnm, float* __restrict__ bni, float invN) {
  int i = blockIdx.x * 256 + threadIdx.x;
  if (i < DD) {
    float m = cs[i] * invN;
    float v = csq[i] * invN - m * m;
    bnm[i] = m;
    bni[i] = rsqrtf(v + 1e-5f);
  }
}

__global__ __launch_bounds__(128) void k_asum(float* __restrict__ alpha, const int* __restrict__ lens) {
  int b = blockIdx.x;
  int t = threadIdx.x;
  int len = lens[b];
  float v = (t < len) ? alpha[b * TT + t] : 0.f;
  float s = v;
  for (int o = 32; o > 0; o >>= 1) s += __shfl_down(s, o);
  __shared__ float sw[2];
  if ((t & 63) == 0) sw[t >> 6] = s;
  __syncthreads();
  float S = sw[0] + sw[1] + 1e-9f;
  alpha[b * TT + t] = v / S;
}

__global__ __launch_bounds__(256) void k_U(const float* __restrict__ Hseq,
                                           const float* __restrict__ alpha,
                                           float* __restrict__ U) {
  int b = blockIdx.x;
  int tid = threadIdx.x;
  __shared__ float al[TT];
  if (tid < TT) al[tid] = alpha[b * TT + tid];
  __syncthreads();
  float4 s = make_float4(0.f, 0.f, 0.f, 0.f);
  const float* Hb = Hseq + (size_t)b * TT * DD + tid * 4;
#pragma unroll 4
  for (int t = 0; t < TT; ++t) {
    float a = al[t];
    float4 h = *(const float4*)(Hb + (size_t)t * DD);
    s.x += a * h.x; s.y += a * h.y; s.z += a * h.z; s.w += a * h.w;
  }
  *(float4*)(U + (size_t)b * DD + tid * 4) = s;
}

__global__ __launch_bounds__(256) void k_p2a(const float* __restrict__ U,
                                             const int* __restrict__ emoI,
                                             const int* __restrict__ cauI,
                                             float* __restrict__ chunkEmb) {
  int e = blockIdx.x;
  int tid = threadIdx.x;
  __shared__ float emoS[DD];
  __shared__ float sc[NCK][16];
  const float* Ue = U + (size_t)emoI[e] * DD;
  for (int i = tid; i < DD; i += 256) emoS[i] = Ue[i];
  __syncthreads();
  int w = tid >> 6, lane = tid & 63;
  for (int p = w; p < 128; p += 4) {
    const float* y = U + (size_t)cauI[p] * DD;
    float s = 0;
    for (int d = lane; d < DD; d += 64) s += emoS[d] * y[d];
    for (int o = 32; o > 0; o >>= 1) s += __shfl_down(s, o);
    if (lane == 0) sc[p >> 4][p & 15] = s;
  }
  __syncthreads();
  if (tid < NCK) {
    float mx = -1e30f;
    for (int c = 0; c < 16; ++c) mx = fmaxf(mx, sc[tid][c]);
    float sum = 0;
    for (int c = 0; c < 16; ++c) {
      float ev = __expf(sc[tid][c] - mx);
      sc[tid][c] = ev;
      sum += ev;
    }
    float inv = 1.f / sum;
    for (int c = 0; c < 16; ++c) sc[tid][c] *= inv;
  }
  __syncthreads();
  int d = tid * 4;
  for (int nn = 0; nn < NCK; ++nn) {
    float4 s = make_float4(0.f, 0.f, 0.f, 0.f);
    for (int c = 0; c < 16; ++c) {
      float wc = sc[nn][c];
      float4 y = *(const float4*)(U + (size_t)cauI[nn * 16 + c] * DD + d);
      s.x += wc * y.x; s.y += wc * y.y; s.z += wc * y.z; s.w += wc * y.w;
    }
    *(float4*)(chunkEmb + ((size_t)e * NCK + nn) * DD + d) = s;
  }
}

__global__ __launch_bounds__(256) void k_delta2(const float* __restrict__ U,
                                                const int* __restrict__ emoI,
                                                const float* __restrict__ chunkEmb,
                                                const float* __restrict__ pos,
                                                float* __restrict__ delta2) {
  int e = blockIdx.x >> 3, nn = blockIdx.x & 7;
  int tid = threadIdx.x;
  const float* emo = U + (size_t)emoI[e] * DD;
  const float* y = chunkEmb + ((size_t)e * NCK + nn) * DD;
  __shared__ float s4[4];
  float ds = 0;
  for (int d = tid; d < DD; d += 256) {
    float df = emo[d] - y[d];
    ds += df * df;
  }
  float dist = sqrtf(blk_sum(ds, s4));
  float* out = delta2 + ((size_t)e * NCK + nn) * K3PAD;
  for (int c = tid; c < K3PAD; c += 256) {
    float v;
    if (c < 1024) v = emo[c];
    else if (c < 2048) v = y[c - 1024];
    else if (c == 2048) v = dist;
    else if (c < 3073) { int d = c - 2049; v = emo[d] * y[d]; }
    else if (c < 3123) v = pos[((size_t)e * NCK + nn) * PPP + (c - 3073)];
    else v = 0.f;
    out[c] = v;
  }
}

__global__ __launch_bounds__(256) void k_bnstats(const float* __restrict__ X,
                                                 float* __restrict__ bm, float* __restrict__ bi, int R) {
  int gid = blockIdx.x * 256 + threadIdx.x;  // NE*DD
  int e = gid >> 10, col = gid & 1023;
  const float* p = X + (size_t)e * R * DD + col;
  float s = 0, s2 = 0;
  for (int r = 0; r < R; ++r) {
    float v = p[(size_t)r * DD];
    s += v;
    s2 += v * v;
  }
  float m = s / R;
  float var = s2 / R - m * m;
  bm[gid] = m;
  bi[gid] = rsqrtf(var + 1e-5f);
}

__global__ __launch_bounds__(256) void k_out2(const float* __restrict__ h2,
                                              const float* __restrict__ bm, const float* __restrict__ bi,
                                              const float* __restrict__ Wo, const float* __restrict__ Wob,
                                              float* __restrict__ out, float* __restrict__ extraf) {
  int e = blockIdx.x >> 3, nn = blockIdx.x & 7;
  int tid = threadIdx.x;
  const float* row = h2 + ((size_t)e * NCK + nn) * DD;
  float l0 = 0, l1 = 0;
  for (int col = tid; col < DD; col += 256) {
    float h = leakyf((row[col] - bm[e * DD + col]) * bi[e * DD + col]);
    l0 += h * Wo[col];
    l1 += h * Wo[DD + col];
  }
  __shared__ float s4[4];
  l0 = blk_sum(l0, s4);
  l1 = blk_sum(l1, s4);
  if (tid == 0) {
    l0 += Wob[0];
    l1 += Wob[1];
    float mx = fmaxf(l0, l1);
    float lse = mx + logf(__expf(l0 - mx) + __expf(l1 - mx));
    out[((size_t)e * NCK + nn) * 2 + 0] = l0 - lse;
    out[((size_t)e * NCK + nn) * 2 + 1] = l1 - lse;
    extraf[e * NCK + nn] = (l1 > l0) ? 1.f : 0.f;
  }
}

__global__ __launch_bounds__(256) void k_delta3(const float* __restrict__ U,
                                                const int* __restrict__ emoI,
                                                const int* __restrict__ cauI,
                                                const float* __restrict__ dis,
                                                const float* __restrict__ extraf,
                                                float* __restrict__ delta3) {
  int e = blockIdx.x >> 7, c = blockIdx.x & 127;
  int tid = threadIdx.x;
  const float* emo = U + (size_t)emoI[e] * DD;
  const float* y = U + (size_t)cauI[c] * DD;
  __shared__ float s4[4];
  float ds = 0;
  for (int d = tid; d < DD; d += 256) {
    float df = emo[d] - y[d];
    ds += df * df;
  }
  float dist = sqrtf(blk_sum(ds, s4));
  float ex = extraf[e * NCK + (c >> 4)];
  float* out = delta3 + ((size_t)e * NCC + c) * K3PAD;
  for (int col = tid; col < K3PAD; col += 256) {
    float v;
    if (col < 1024) v = emo[col];
    else if (col < 2048) v = y[col - 1024];
    else if (col == 2048) v = dist;
    else if (col < 3073) { int d = col - 2049; v = emo[d] * y[d]; }
    else if (col < 3123) v = dis[((size_t)e * NCC + c) * PPP + (col - 3073)];
    else if (col < 3173) v = ex;
    else v = 0.f;
    out[col] = v;
  }
}

__global__ __launch_bounds__(256) void k_p3(const float* __restrict__ h3,
                                            const float* __restrict__ bm, const float* __restrict__ bi,
                                            const float* __restrict__ cw, const float* __restrict__ cb,
                                            float* __restrict__ out) {
  int e = blockIdx.x >> 7, c = blockIdx.x & 127;
  int tid = threadIdx.x;
  const float* row = h3 + ((size_t)e * NCC + c) * DD;
  float l0 = 0, l1 = 0;
  for (int col = tid; col < DD; col += 256) {
    float h = leakyf((row[col] - bm[e * DD + col]) * bi[e * DD + col]);
    l0 += h * cw[col];
    l1 += h * cw[DD + col];
  }
  __shared__ float s4[4];
  l0 = blk_sum(l0, s4);
  l1 = blk_sum(l1, s4);
  if (tid == 0) {
    l0 += cb[0];
    l1 += cb[1];
    float mx = fmaxf(l0, l1);
    float lse = mx + logf(__expf(l0 - mx) + __expf(l1 - mx));
    out[((size_t)e * NCC + c) * 2 + 0] = l0 - lse;
    out[((size_t)e * NCC + c) * 2 + 1] = l1 - lse;
  }
}

__global__ __launch_bounds__(256) void k_L(const int* __restrict__ lab, float* __restrict__ out) {
  int i = blockIdx.x * 256 + threadIdx.x;  // 8192
  int e = i >> 7, c = i & 127;
  int a = lab[e * 3 + 0], b = lab[e * 3 + 1], d = lab[e * 3 + 2];
  out[i] = (a == c || b == c || d == c) ? 1.f : 0.f;
}

extern "C" void kernel_launch(void* const* d_in, const int* in_sizes, int n_in,
                              void* d_out, int out_size, void* d_ws, size_t ws_size,
                              hipStream_t stream) {
  (void)in_sizes; (void)n_in; (void)out_size; (void)ws_size;
  const float* X     = (const float*)d_in[0];
  const float* pos   = (const float*)d_in[1];
  const float* dis   = (const float*)d_in[2];
  const int*   lens  = (const int*)d_in[3];
  const int*   lab3  = (const int*)d_in[4];
  const int*   emoI  = (const int*)d_in[5];
  const int*   cauI  = (const int*)d_in[6];
  const float* Wih_f = (const float*)d_in[7];
  const float* Whh_f = (const float*)d_in[8];
  const float* bih_f = (const float*)d_in[9];
  const float* bhh_f = (const float*)d_in[10];
  const float* Wih_b = (const float*)d_in[11];
  const float* Whh_b = (const float*)d_in[12];
  const float* bih_b = (const float*)d_in[13];
  const float* bhh_b = (const float*)d_in[14];
  const float* s1w   = (const float*)d_in[15];
  const float* s1b   = (const float*)d_in[16];
  const float* s2w   = (const float*)d_in[17];
  const float* W2w   = (const float*)d_in[18];
  const float* W2b   = (const float*)d_in[19];
  const float* Wow   = (const float*)d_in[20];
  const float* Wob   = (const float*)d_in[21];
  const float* W3w   = (const float*)d_in[22];
  const float* W3b   = (const float*)d_in[23];
  const float* clsw  = (const float*)d_in[24];
  const float* clsb  = (const float*)d_in[25];
  float* ws = (float*)d_ws;
  float* out = (float*)d_out;

  unsigned short* WIHhi = (unsigned short*)(ws + F_WIH);
  unsigned short* WIHlo = WIHhi + (size_t)2 * 2048 * 1024;
  unsigned short* WHHhi = (unsigned short*)(ws + F_WHH);
  unsigned short* WHHlo = WHHhi + (size_t)2 * 2048 * 512;
  unsigned short* S1hi  = (unsigned short*)(ws + F_S1);
  unsigned short* S1lo  = S1hi + (size_t)1024 * 1024;
  unsigned short* W2hi  = (unsigned short*)(ws + F_W2);
  unsigned short* W2lo  = W2hi + (size_t)1024 * K3PAD;
  unsigned short* W3hi  = (unsigned short*)(ws + F_W3);
  unsigned short* W3lo  = W3hi + (size_t)1024 * K3PAD;

  // zero-init read-before-write buffers (padded Hseq rows MUST be 0 for BN stats)
  hipMemsetAsync(ws + F_HSEQ, 0, (size_t)33554432 * sizeof(float), stream);
  hipMemsetAsync(ws + F_HST, 0, (size_t)(524288 + 262144) * sizeof(float), stream);  // HST + CST
  hipMemsetAsync(ws + F_CS, 0, (size_t)2048 * sizeof(float), stream);                // CS + CSQ
  hipMemsetAsync(ws + F_ALPHA, 0, (size_t)32768 * sizeof(float), stream);

  // weight converts (fp32 -> bf16 hi/lo, n-major = native torch layout)
  k_cvt<<<2048, 256, 0, stream>>>(Wih_f, WIHhi, WIHlo, 1024, 1024);
  k_cvt<<<2048, 256, 0, stream>>>(Wih_b, WIHhi + (size_t)2048 * 1024, WIHlo + (size_t)2048 * 1024, 1024, 1024);
  k_cvt<<<2048, 256, 0, stream>>>(Whh_f, WHHhi, WHHlo, 512, 512);
  k_cvt<<<2048, 256, 0, stream>>>(Whh_b, WHHhi + (size_t)2048 * 512, WHHlo + (size_t)2048 * 512, 512, 512);
  k_cvt<<<1024, 256, 0, stream>>>(s1w, S1hi, S1lo, 1024, 1024);
  k_cvt<<<1024, 256, 0, stream>>>(W2w, W2hi, W2lo, 3123, K3PAD);
  k_cvt<<<1024, 256, 0, stream>>>(W3w, W3hi, W3lo, 3173, K3PAD);
  k_biasc<<<16, 256, 0, stream>>>(bih_f, bhh_f, bih_b, bhh_b, ws + F_BIASC);

  // BiLSTM: chunked input-projection MFMA GEMMs + per-step (h@Whh MFMA, cell)
  for (int c = 0; c < TT / CHUNK; ++c) {
    k_mf<3><<<dim3(16, 16, 2), 256, 0, stream>>>(X, WIHhi, WIHlo, ws + F_BIASC, ws + F_XG,
                                                 2048, 2048, 1024, lens, c,
                                                 nullptr, nullptr, nullptr, nullptr, nullptr, nullptr);
    for (int tt = 0; tt < CHUNK; ++tt) {
      int t = c * CHUNK + tt;
      const float* Hcur = ws + F_HST + (size_t)(t & 1) * 262144;
      float* Hnext = ws + F_HST + (size_t)((t + 1) & 1) * 262144;
      k_mf<4><<<dim3(2, 16, 2), 256, 0, stream>>>(Hcur, WHHhi, WHHlo, nullptr, ws + F_GW,
                                                  256, 2048, 512, nullptr, 0,
                                                  nullptr, nullptr, nullptr, nullptr, nullptr, nullptr);
      k_cell<<<256, 256, 0, stream>>>(ws + F_XG, ws + F_GW, lens, Hcur, Hnext,
                                      ws + F_CST, ws + F_HSEQ, t);
    }
  }

  // attention: two-pass z (BN stats, then masked-linear attention weights)
  k_mf<1><<<dim3(256, 8), 256, 0, stream>>>(ws + F_HSEQ, S1hi, S1lo, s1b, nullptr,
                                            NROWS, 1024, 1024, nullptr, 0,
                                            nullptr, nullptr, nullptr,
                                            ws + F_CS, ws + F_CSQ, nullptr);
  k_bnfinal<<<4, 256, 0, stream>>>(ws + F_CS, ws + F_CSQ, ws + F_BNM, ws + F_BNI, 1.f / NROWS);
  k_mf<2><<<dim3(256, 8), 256, 0, stream>>>(ws + F_HSEQ, S1hi, S1lo, s1b, nullptr,
                                            NROWS, 1024, 1024, nullptr, 0,
                                            ws + F_BNM, ws + F_BNI, s2w,
                                            nullptr, nullptr, ws + F_ALPHA);
  k_asum<<<BB, TT, 0, stream>>>(ws + F_ALPHA, lens);
  k_U<<<BB, 256, 0, stream>>>(ws + F_HSEQ, ws + F_ALPHA, ws + F_U);

  // phase 2 (D2/CHE overlay dead Hseq region)
  k_p2a<<<NE, 256, 0, stream>>>(ws + F_U, emoI, cauI, ws + F_CHE);
  k_delta2<<<NE * NCK, 256, 0, stream>>>(ws + F_U, emoI, ws + F_CHE, pos, ws + F_D2);
  k_mf<0><<<dim3(4, 8), 256, 0, stream>>>(ws + F_D2, W2hi, W2lo, W2b, ws + F_H2,
                                          512, 1024, K3PAD, nullptr, 0,
                                          nullptr, nullptr, nullptr, nullptr, nullptr, nullptr);
  k_bnstats<<<256, 256, 0, stream>>>(ws + F_H2, ws + F_BN2M, ws + F_BN2I, NCK);
  k_out2<<<NE * NCK, 256, 0, stream>>>(ws + F_H2, ws + F_BN2M, ws + F_BN2I, Wow, Wob,
                                       out, ws + F_EXTRA);

  // phase 3 (D3 overlays Hseq; H3 overlays dead XG)
  k_delta3<<<NE * NCC, 256, 0, stream>>>(ws + F_U, emoI, cauI, dis, ws + F_EXTRA, ws + F_D3);
  k_mf<0><<<dim3(64, 8), 256, 0, stream>>>(ws + F_D3, W3hi, W3lo, W3b, ws + F_H3,
                                           8192, 1024, K3PAD, nullptr, 0,
                                           nullptr, nullptr, nullptr, nullptr, nullptr, nullptr);
  k_bnstats<<<256, 256, 0, stream>>>(ws + F_H3, ws + F_BN3M, ws + F_BN3I, NCC);
  k_p3<<<NE * NCC, 256, 0, stream>>>(ws + F_H3, ws + F_BN3M, ws + F_BN3I, clsw, clsb, out + 1024);
  k_L<<<32, 256, 0, stream>>>(lab3, out + 17408);
}

// Round 4
// 4733.785 us; speedup vs baseline: 8.4479x; 1.3023x over previous
//
#include <hip/hip_runtime.h>
#include <math.h>

// ---------------- problem dims ----------------
#define DD    1024
#define TT    128
#define BB    256
#define NE    64
#define NCC   128
#define PPP   50
#define NCK   8
#define HH    512
#define G4    2048     // 4*HH
#define NROWS 32768    // BB*TT
#define K3PAD 3200     // padded K for phase2/3 GEMMs (3123 / 3173 -> 3200)
#define CHUNK 8        // timesteps per XG chunk

// ---------------- workspace layout (float offsets) ----------------
#define F_HSEQ  0ull            // Hseq hi [32768][1024] u16 + lo (33,554,432 float-slots); later D2/CHE/D3
#define F_XG    33554432ull     // [2][CHUNK][256][2048] fp32 8,388,608 ; later H3
#define F_WIH   41943040ull     // bf16 hi[2][2048][1024] + lo  (4,194,304 float-slots)
#define F_WHH   46137344ull     // bf16 hi[2][2048][512] + lo   (2,097,152)
#define F_S1    48234496ull     // bf16 hi[1024][1024] + lo     (1,048,576)
#define F_W2    49283072ull     // bf16 hi[1024][3200] + lo     (3,276,800)
#define F_W3    52559872ull     // bf16 hi[1024][3200] + lo     (3,276,800)
#define F_BIASC 56885248ull     // [2][2048]
#define F_HST   56889344ull     // 2 buf x [2][256][512] = 524,288
#define F_CST   57413632ull     // [2][256][512] = 262,144
#define F_CS    57675776ull
#define F_CSQ   57676800ull
#define F_BNM   57677824ull
#define F_BNI   57678848ull
#define F_ALPHA 57679872ull     // [BB*TT]
#define F_U     57712640ull     // [BB,DD] 262,144
#define F_H2    57974784ull     // [64,8,1024] 524,288
#define F_BN2M  58499072ull
#define F_BN2I  58564608ull
#define F_EXTRA 58630144ull
#define F_BN3M  58631168ull
#define F_BN3I  58696704ull

#define F_D2    F_HSEQ
#define F_CHE   (F_HSEQ + 26214400ull)
#define F_D3    F_HSEQ
#define F_H3    F_XG

typedef short s8v __attribute__((ext_vector_type(8)));
typedef float f4v __attribute__((ext_vector_type(4)));

__device__ __forceinline__ float leakyf(float x) { return x >= 0.f ? x : 0.01f * x; }
__device__ __forceinline__ float sigmf(float x)  { return 1.f / (1.f + __expf(-x)); }

__device__ __forceinline__ float blk_sum(float v, float* s4) {
  for (int o = 32; o > 0; o >>= 1) v += __shfl_down(v, o);
  __syncthreads();
  if ((threadIdx.x & 63) == 0) s4[threadIdx.x >> 6] = v;
  __syncthreads();
  return s4[0] + s4[1] + s4[2] + s4[3];
}

// pack 2 fp32 -> (hi bf16 pair, lo bf16 pair); hi = truncation, lo = exact residual truncated
__device__ __forceinline__ void cvt2(float x0, float x1, unsigned& hi, unsigned& lo) {
  unsigned b0 = __float_as_uint(x0), b1 = __float_as_uint(x1);
  hi = (b0 >> 16) | (b1 & 0xffff0000u);
  float h0 = __uint_as_float(b0 & 0xffff0000u);
  float h1 = __uint_as_float(b1 & 0xffff0000u);
  unsigned l0 = __float_as_uint(x0 - h0);
  unsigned l1 = __float_as_uint(x1 - h1);
  lo = (l0 >> 16) | (l1 & 0xffff0000u);
}

// weight convert: src fp32 [N][Ks] row-major -> hi/lo bf16 [N][Kd] (zero-padded)
__global__ __launch_bounds__(256) void k_cvt(const float* __restrict__ src,
                                             unsigned short* __restrict__ hi,
                                             unsigned short* __restrict__ lo,
                                             int Ks, int Kd) {
  int n = blockIdx.x;
  for (int k = threadIdx.x; k < Kd; k += 256) {
    float v = (k < Ks) ? src[(size_t)n * Ks + k] : 0.f;
    unsigned b = __float_as_uint(v);
    float h = __uint_as_float(b & 0xffff0000u);
    hi[(size_t)n * Kd + k] = (unsigned short)(b >> 16);
    lo[(size_t)n * Kd + k] = (unsigned short)(__float_as_uint(v - h) >> 16);
  }
}

__global__ __launch_bounds__(256) void k_biasc(const float* __restrict__ bf1, const float* __restrict__ bf2,
                                               const float* __restrict__ bb1, const float* __restrict__ bb2,
                                               float* __restrict__ out) {
  int i = blockIdx.x * 256 + threadIdx.x;  // 4096
  if (i < G4) out[i] = bf1[i] + bf2[i];
  else        out[i] = bb1[i - G4] + bb2[i - G4];
}

// ---------------- MFMA GEMM, 128x128 tile, split-bf16 3-term (fp32-accurate) ----------------
// B bf16 hi/lo n-major [N][K].
// MODE 0 STORE: A fp32; C = A@B + bias                         (p2/p3 GEMMs)
// MODE 1 STATS: A pre-split hi/lo; atomic col sum/sumsq        (z pass 1)
// MODE 2 ALPHA: A pre-split hi/lo; atomic row sum of leaky((z-bnm)*bni)*s2w  (z pass 2)
// MODE 3 XG:    A fp32 rows gathered from X via lens; dir = blockIdx.z
template <int MODE>
__global__ __launch_bounds__(256, 2) void k_mf(
    const float* __restrict__ A,
    const unsigned short* __restrict__ Ahi, const unsigned short* __restrict__ Alo,
    const unsigned short* __restrict__ Bhi, const unsigned short* __restrict__ Blo,
    const float* __restrict__ bias, float* __restrict__ C, int M, int N, int K,
    const int* __restrict__ lens, int c,
    const float* __restrict__ bnm, const float* __restrict__ bni,
    const float* __restrict__ s2w, float* __restrict__ cs,
    float* __restrict__ csq, float* __restrict__ alpha) {
  __shared__ unsigned short Ah[128][40];
  __shared__ unsigned short Al[128][40];
  __shared__ unsigned short Bh[128][40];
  __shared__ unsigned short Bl[128][40];
  const int tid = threadIdx.x;
  const int m0 = blockIdx.x * 128;
  const int n0 = blockIdx.y * 128;
  const int dir = (MODE == 3) ? blockIdx.z : 0;

  const int sr = tid >> 1;
  const int sh = tid & 1;
  const float* arow = nullptr;
  const unsigned short* ahrow = nullptr;
  const unsigned short* alrow = nullptr;
  if (MODE == 3) {
    int tl = m0 >> 8;
    int b = (m0 & 255) + sr;
    int t = c * CHUNK + tl;
    int len = lens[b];
    int r = (dir == 0) ? t : ((t < len) ? (len - 1 - t) : t);
    arow = A + ((size_t)b * TT + r) * DD;
  } else if (MODE == 0) {
    arow = A + (size_t)(m0 + sr) * K;
  } else {
    ahrow = Ahi + (size_t)(m0 + sr) * K;
    alrow = Alo + (size_t)(m0 + sr) * K;
  }
  const unsigned short* bhrow = Bhi + ((size_t)dir * N + n0 + sr) * K;
  const unsigned short* blrow = Blo + ((size_t)dir * N + n0 + sr) * K;

  const int wave = tid >> 6, lane = tid & 63;
  const int wm = wave & 1, wn = wave >> 1;
  const int quad = lane >> 4, l15 = lane & 15;

  f4v acc[4][4];
#pragma unroll
  for (int i = 0; i < 4; ++i)
#pragma unroll
    for (int j = 0; j < 4; ++j) acc[i][j] = (f4v){0.f, 0.f, 0.f, 0.f};

#pragma unroll 1
  for (int k0 = 0; k0 < K; k0 += 32) {
    __syncthreads();
    if (MODE == 1 || MODE == 2) {
      const uint4* ph = (const uint4*)(ahrow + k0 + sh * 16);
      uint4* dh = (uint4*)&Ah[sr][sh * 16];
      dh[0] = ph[0]; dh[1] = ph[1];
      const uint4* pl = (const uint4*)(alrow + k0 + sh * 16);
      uint4* dl = (uint4*)&Al[sr][sh * 16];
      dl[0] = pl[0]; dl[1] = pl[1];
    } else {
      const float4* pa = (const float4*)(arow + k0 + sh * 16);
      float4 v0 = pa[0], v1 = pa[1], v2 = pa[2], v3 = pa[3];
      unsigned h[8], l[8];
      cvt2(v0.x, v0.y, h[0], l[0]); cvt2(v0.z, v0.w, h[1], l[1]);
      cvt2(v1.x, v1.y, h[2], l[2]); cvt2(v1.z, v1.w, h[3], l[3]);
      cvt2(v2.x, v2.y, h[4], l[4]); cvt2(v2.z, v2.w, h[5], l[5]);
      cvt2(v3.x, v3.y, h[6], l[6]); cvt2(v3.z, v3.w, h[7], l[7]);
      uint4* dh = (uint4*)&Ah[sr][sh * 16];
      dh[0] = make_uint4(h[0], h[1], h[2], h[3]);
      dh[1] = make_uint4(h[4], h[5], h[6], h[7]);
      uint4* dl = (uint4*)&Al[sr][sh * 16];
      dl[0] = make_uint4(l[0], l[1], l[2], l[3]);
      dl[1] = make_uint4(l[4], l[5], l[6], l[7]);
    }
    {
      const uint4* pbh = (const uint4*)(bhrow + k0 + sh * 16);
      uint4* dbh = (uint4*)&Bh[sr][sh * 16];
      dbh[0] = pbh[0]; dbh[1] = pbh[1];
      const uint4* pbl = (const uint4*)(blrow + k0 + sh * 16);
      uint4* dbl = (uint4*)&Bl[sr][sh * 16];
      dbl[0] = pbl[0]; dbl[1] = pbl[1];
    }
    __syncthreads();
    s8v ah[4], al[4], bh[4], bl[4];
#pragma unroll
    for (int mi = 0; mi < 4; ++mi) {
      ah[mi] = *(const s8v*)&Ah[wm * 64 + mi * 16 + l15][quad * 8];
      al[mi] = *(const s8v*)&Al[wm * 64 + mi * 16 + l15][quad * 8];
    }
#pragma unroll
    for (int ni = 0; ni < 4; ++ni) {
      bh[ni] = *(const s8v*)&Bh[wn * 64 + ni * 16 + l15][quad * 8];
      bl[ni] = *(const s8v*)&Bl[wn * 64 + ni * 16 + l15][quad * 8];
    }
#pragma unroll
    for (int mi = 0; mi < 4; ++mi)
#pragma unroll
      for (int ni = 0; ni < 4; ++ni) {
        acc[mi][ni] = __builtin_amdgcn_mfma_f32_16x16x32_bf16(ah[mi], bh[ni], acc[mi][ni], 0, 0, 0);
        acc[mi][ni] = __builtin_amdgcn_mfma_f32_16x16x32_bf16(al[mi], bh[ni], acc[mi][ni], 0, 0, 0);
        acc[mi][ni] = __builtin_amdgcn_mfma_f32_16x16x32_bf16(ah[mi], bl[ni], acc[mi][ni], 0, 0, 0);
      }
  }

  // epilogue; C/D layout: col = l15, row = quad*4 + reg
  const int rb = wm * 64;
  if (MODE == 0 || MODE == 3) {
    float* Cb;
    const float* bp = bias;
    if (MODE == 3) {
      int tl = m0 >> 8;
      Cb = C + (((size_t)dir * CHUNK + tl) * 256 + (m0 & 255)) * (size_t)N;
      bp = bias + (size_t)dir * N;
    } else {
      Cb = C + (size_t)m0 * N;
    }
#pragma unroll
    for (int mi = 0; mi < 4; ++mi)
#pragma unroll
      for (int ni = 0; ni < 4; ++ni) {
        int col = n0 + wn * 64 + ni * 16 + l15;
        float bv = bp[col];
#pragma unroll
        for (int r = 0; r < 4; ++r) {
          int row = rb + mi * 16 + quad * 4 + r;
          Cb[(size_t)row * N + col] = acc[mi][ni][r] + bv;
        }
      }
  } else if (MODE == 1) {
#pragma unroll
    for (int ni = 0; ni < 4; ++ni) {
      int col = n0 + wn * 64 + ni * 16 + l15;
      float bv = bias[col];
      float s = 0.f, q = 0.f;
#pragma unroll
      for (int mi = 0; mi < 4; ++mi)
#pragma unroll
        for (int r = 0; r < 4; ++r) {
          float z = acc[mi][ni][r] + bv;
          s += z;
          q += z * z;
        }
      s += __shfl_xor(s, 16); s += __shfl_xor(s, 32);
      q += __shfl_xor(q, 16); q += __shfl_xor(q, 32);
      if (quad == 0) {
        atomicAdd(&cs[col], s);
        atomicAdd(&csq[col], q);
      }
    }
  } else {  // MODE 2
#pragma unroll
    for (int mi = 0; mi < 4; ++mi) {
      float rv[4] = {0.f, 0.f, 0.f, 0.f};
#pragma unroll
      for (int ni = 0; ni < 4; ++ni) {
        int col = n0 + wn * 64 + ni * 16 + l15;
        float bv = bias[col], mc = bnm[col], ic = bni[col], wc = s2w[col];
#pragma unroll
        for (int r = 0; r < 4; ++r) {
          float z = acc[mi][ni][r] + bv;
          rv[r] += leakyf((z - mc) * ic) * wc;
        }
      }
#pragma unroll
      for (int r = 0; r < 4; ++r) {
        float v = rv[r];
        v += __shfl_xor(v, 1); v += __shfl_xor(v, 2);
        v += __shfl_xor(v, 4); v += __shfl_xor(v, 8);
        if (l15 == 0) atomicAdd(&alpha[m0 + rb + mi * 16 + quad * 4 + r], v);
      }
    }
  }
}

// ---------------- fused LSTM step: gates = h@Whh^T (4-gate gathered cols) + XG; cell update ----------------
// grid (4 btiles x 64, 32 jtiles x 16, 2 dirs), 256 threads = 4 waves
// wave w: rows b0+w*16..+15; frags acc[g] cover cols {g*512 + j0 + l15}
// epilogue: each thread holds ALL FOUR gates for its (b, j) pairs -> inline cell update
__global__ __launch_bounds__(256, 2) void k_rec(
    const unsigned short* __restrict__ Bhi, const unsigned short* __restrict__ Blo,
    const float* __restrict__ XG, const int* __restrict__ lens,
    const float* __restrict__ Hcur, float* __restrict__ Hnext,
    float* __restrict__ Cst,
    unsigned short* __restrict__ Hhi, unsigned short* __restrict__ Hlo, int t) {
  __shared__ unsigned short Ah[64][40];
  __shared__ unsigned short Al[64][40];
  __shared__ unsigned short Bh[64][40];
  __shared__ unsigned short Bl[64][40];
  const int tid = threadIdx.x;
  const int b0 = blockIdx.x * 64;
  const int j0 = blockIdx.y * 16;
  const int dir = blockIdx.z;
  const int tl = t & (CHUNK - 1);
  const int srow = tid >> 2;          // 0..63
  const int skq = (tid & 3) * 8;      // k-octet within 32
  const int bg = srow >> 4, bjj = srow & 15;
  const float* arow = Hcur + ((size_t)dir * BB + b0 + srow) * HH;
  const unsigned short* bhrow = Bhi + ((size_t)dir * G4 + bg * HH + j0 + bjj) * HH;
  const unsigned short* blrow = Blo + ((size_t)dir * G4 + bg * HH + j0 + bjj) * HH;
  const int wave = tid >> 6, lane = tid & 63;
  const int quad = lane >> 4, l15 = lane & 15;

  f4v acc[4];
#pragma unroll
  for (int g = 0; g < 4; ++g) acc[g] = (f4v){0.f, 0.f, 0.f, 0.f};

#pragma unroll 1
  for (int k0 = 0; k0 < HH; k0 += 32) {
    __syncthreads();
    {
      const float4* pa = (const float4*)(arow + k0 + skq);
      float4 v0 = pa[0], v1 = pa[1];
      unsigned h[4], l[4];
      cvt2(v0.x, v0.y, h[0], l[0]); cvt2(v0.z, v0.w, h[1], l[1]);
      cvt2(v1.x, v1.y, h[2], l[2]); cvt2(v1.z, v1.w, h[3], l[3]);
      *(uint4*)&Ah[srow][skq] = make_uint4(h[0], h[1], h[2], h[3]);
      *(uint4*)&Al[srow][skq] = make_uint4(l[0], l[1], l[2], l[3]);
      *(uint4*)&Bh[srow][skq] = *(const uint4*)(bhrow + k0 + skq);
      *(uint4*)&Bl[srow][skq] = *(const uint4*)(blrow + k0 + skq);
    }
    __syncthreads();
    s8v ah = *(const s8v*)&Ah[wave * 16 + l15][quad * 8];
    s8v al = *(const s8v*)&Al[wave * 16 + l15][quad * 8];
#pragma unroll
    for (int g = 0; g < 4; ++g) {
      s8v bh = *(const s8v*)&Bh[g * 16 + l15][quad * 8];
      s8v bl = *(const s8v*)&Bl[g * 16 + l15][quad * 8];
      acc[g] = __builtin_amdgcn_mfma_f32_16x16x32_bf16(ah, bh, acc[g], 0, 0, 0);
      acc[g] = __builtin_amdgcn_mfma_f32_16x16x32_bf16(al, bh, acc[g], 0, 0, 0);
      acc[g] = __builtin_amdgcn_mfma_f32_16x16x32_bf16(ah, bl, acc[g], 0, 0, 0);
    }
  }

  const int j = j0 + l15;
#pragma unroll
  for (int r = 0; r < 4; ++r) {
    int b = b0 + wave * 16 + quad * 4 + r;
    int len = lens[b];
    bool m = t < len;
    size_t xgb = (((size_t)dir * CHUNK + tl) * BB + b) * G4 + j;
    float gi = acc[0][r] + XG[xgb];
    float gf = acc[1][r] + XG[xgb + HH];
    float gg = acc[2][r] + XG[xgb + 2 * HH];
    float go = acc[3][r] + XG[xgb + 3 * HH];
    size_t sidx = ((size_t)dir * BB + b) * HH + j;
    float c_old = Cst[sidx];
    float cn = sigmf(gf) * c_old + sigmf(gi) * tanhf(gg);
    float hn = sigmf(go) * tanhf(cn);
    if (m) {
      Cst[sidx] = cn;
      Hnext[sidx] = hn;
      int ro = dir ? (len - 1 - t) : t;
      size_t hidx = ((size_t)b * TT + ro) * DD + dir * HH + j;
      unsigned hb = __float_as_uint(hn);
      Hhi[hidx] = (unsigned short)(hb >> 16);
      Hlo[hidx] = (unsigned short)(__float_as_uint(hn - __uint_as_float(hb & 0xffff0000u)) >> 16);
    } else {
      Hnext[sidx] = Hcur[sidx];
    }
  }
}

__global__ __launch_bounds__(256) void k_bnfinal(const float* __restrict__ cs, const float* __restrict__ csq,
                                                 float* __restrict__ bnm, float* __restrict__ bni, float invN) {
  int i = blockIdx.x * 256 + threadIdx.x;
  if (i < DD) {
    float m = cs[i] * invN;
    float v = csq[i] * invN - m * m;
    bnm[i] = m;
    bni[i] = rsqrtf(v + 1e-5f);
  }
}

__global__ __launch_bounds__(128) void k_asum(float* __restrict__ alpha, const int* __restrict__ lens) {
  int b = blockIdx.x;
  int t = threadIdx.x;
  int len = lens[b];
  float v = (t < len) ? alpha[b * TT + t] : 0.f;
  float s = v;
  for (int o = 32; o > 0; o >>= 1) s += __shfl_down(s, o);
  __shared__ float sw[2];
  if ((t & 63) == 0) sw[t >> 6] = s;
  __syncthreads();
  float S = sw[0] + sw[1] + 1e-9f;
  alpha[b * TT + t] = v / S;
}

__global__ __launch_bounds__(256) void k_U(const unsigned short* __restrict__ Hhi,
                                           const unsigned short* __restrict__ Hlo,
                                           const float* __restrict__ alpha,
                                           float* __restrict__ U) {
  int b = blockIdx.x;
  int tid = threadIdx.x;
  __shared__ float al[TT];
  if (tid < TT) al[tid] = alpha[b * TT + tid];
  __syncthreads();
  float4 s = make_float4(0.f, 0.f, 0.f, 0.f);
  size_t base = (size_t)b * TT * DD + tid * 4;
#pragma unroll 4
  for (int t = 0; t < TT; ++t) {
    float a = al[t];
    ushort4 hv = *(const ushort4*)(Hhi + base + (size_t)t * DD);
    ushort4 lv = *(const ushort4*)(Hlo + base + (size_t)t * DD);
    s.x += a * (__uint_as_float((unsigned)hv.x << 16) + __uint_as_float((unsigned)lv.x << 16));
    s.y += a * (__uint_as_float((unsigned)hv.y << 16) + __uint_as_float((unsigned)lv.y << 16));
    s.z += a * (__uint_as_float((unsigned)hv.z << 16) + __uint_as_float((unsigned)lv.z << 16));
    s.w += a * (__uint_as_float((unsigned)hv.w << 16) + __uint_as_float((unsigned)lv.w << 16));
  }
  *(float4*)(U + (size_t)b * DD + tid * 4) = s;
}

__global__ __launch_bounds__(256) void k_p2a(const float* __restrict__ U,
                                             const int* __restrict__ emoI,
                                             const int* __restrict__ cauI,
                                             float* __restrict__ chunkEmb) {
  int e = blockIdx.x;
  int tid = threadIdx.x;
  __shared__ float emoS[DD];
  __shared__ float sc[NCK][16];
  const float* Ue = U + (size_t)emoI[e] * DD;
  for (int i = tid; i < DD; i += 256) emoS[i] = Ue[i];
  __syncthreads();
  int w = tid >> 6, lane = tid & 63;
  for (int p = w; p < 128; p += 4) {
    const float* y = U + (size_t)cauI[p] * DD;
    float s = 0;
    for (int d = lane; d < DD; d += 64) s += emoS[d] * y[d];
    for (int o = 32; o > 0; o >>= 1) s += __shfl_down(s, o);
    if (lane == 0) sc[p >> 4][p & 15] = s;
  }
  __syncthreads();
  if (tid < NCK) {
    float mx = -1e30f;
    for (int c = 0; c < 16; ++c) mx = fmaxf(mx, sc[tid][c]);
    float sum = 0;
    for (int c = 0; c < 16; ++c) {
      float ev = __expf(sc[tid][c] - mx);
      sc[tid][c] = ev;
      sum += ev;
    }
    float inv = 1.f / sum;
    for (int c = 0; c < 16; ++c) sc[tid][c] *= inv;
  }
  __syncthreads();
  int d = tid * 4;
  for (int nn = 0; nn < NCK; ++nn) {
    float4 s = make_float4(0.f, 0.f, 0.f, 0.f);
    for (int c = 0; c < 16; ++c) {
      float wc = sc[nn][c];
      float4 y = *(const float4*)(U + (size_t)cauI[nn * 16 + c] * DD + d);
      s.x += wc * y.x; s.y += wc * y.y; s.z += wc * y.z; s.w += wc * y.w;
    }
    *(float4*)(chunkEmb + ((size_t)e * NCK + nn) * DD + d) = s;
  }
}

__global__ __launch_bounds__(256) void k_delta2(const float* __restrict__ U,
                                                const int* __restrict__ emoI,
                                                const float* __restrict__ chunkEmb,
                                                const float* __restrict__ pos,
                                                float* __restrict__ delta2) {
  int e = blockIdx.x >> 3, nn = blockIdx.x & 7;
  int tid = threadIdx.x;
  const float* emo = U + (size_t)emoI[e] * DD;
  const float* y = chunkEmb + ((size_t)e * NCK + nn) * DD;
  __shared__ float s4[4];
  float ds = 0;
  for (int d = tid; d < DD; d += 256) {
    float df = emo[d] - y[d];
    ds += df * df;
  }
  float dist = sqrtf(blk_sum(ds, s4));
  float* out = delta2 + ((size_t)e * NCK + nn) * K3PAD;
  for (int c = tid; c < K3PAD; c += 256) {
    float v;
    if (c < 1024) v = emo[c];
    else if (c < 2048) v = y[c - 1024];
    else if (c == 2048) v = dist;
    else if (c < 3073) { int d = c - 2049; v = emo[d] * y[d]; }
    else if (c < 3123) v = pos[((size_t)e * NCK + nn) * PPP + (c - 3073)];
    else v = 0.f;
    out[c] = v;
  }
}

__global__ __launch_bounds__(256) void k_bnstats(const float* __restrict__ X,
                                                 float* __restrict__ bm, float* __restrict__ bi, int R) {
  int gid = blockIdx.x * 256 + threadIdx.x;  // NE*DD
  int e = gid >> 10, col = gid & 1023;
  const float* p = X + (size_t)e * R * DD + col;
  float s = 0, s2 = 0;
  for (int r = 0; r < R; ++r) {
    float v = p[(size_t)r * DD];
    s += v;
    s2 += v * v;
  }
  float m = s / R;
  float var = s2 / R - m * m;
  bm[gid] = m;
  bi[gid] = rsqrtf(var + 1e-5f);
}

__global__ __launch_bounds__(256) void k_out2(const float* __restrict__ h2,
                                              const float* __restrict__ bm, const float* __restrict__ bi,
                                              const float* __restrict__ Wo, const float* __restrict__ Wob,
                                              float* __restrict__ out, float* __restrict__ extraf) {
  int e = blockIdx.x >> 3, nn = blockIdx.x & 7;
  int tid = threadIdx.x;
  const float* row = h2 + ((size_t)e * NCK + nn) * DD;
  float l0 = 0, l1 = 0;
  for (int col = tid; col < DD; col += 256) {
    float h = leakyf((row[col] - bm[e * DD + col]) * bi[e * DD + col]);
    l0 += h * Wo[col];
    l1 += h * Wo[DD + col];
  }
  __shared__ float s4[4];
  l0 = blk_sum(l0, s4);
  l1 = blk_sum(l1, s4);
  if (tid == 0) {
    l0 += Wob[0];
    l1 += Wob[1];
    float mx = fmaxf(l0, l1);
    float lse = mx + logf(__expf(l0 - mx) + __expf(l1 - mx));
    out[((size_t)e * NCK + nn) * 2 + 0] = l0 - lse;
    out[((size_t)e * NCK + nn) * 2 + 1] = l1 - lse;
    extraf[e * NCK + nn] = (l1 > l0) ? 1.f : 0.f;
  }
}

__global__ __launch_bounds__(256) void k_delta3(const float* __restrict__ U,
                                                const int* __restrict__ emoI,
                                                const int* __restrict__ cauI,
                                                const float* __restrict__ dis,
                                                const float* __restrict__ extraf,
                                                float* __restrict__ delta3) {
  int e = blockIdx.x >> 7, c = blockIdx.x & 127;
  int tid = threadIdx.x;
  const float* emo = U + (size_t)emoI[e] * DD;
  const float* y = U + (size_t)cauI[c] * DD;
  __shared__ float s4[4];
  float ds = 0;
  for (int d = tid; d < DD; d += 256) {
    float df = emo[d] - y[d];
    ds += df * df;
  }
  float dist = sqrtf(blk_sum(ds, s4));
  float ex = extraf[e * NCK + (c >> 4)];
  float* out = delta3 + ((size_t)e * NCC + c) * K3PAD;
  for (int col = tid; col < K3PAD; col += 256) {
    float v;
    if (col < 1024) v = emo[col];
    else if (col < 2048) v = y[col - 1024];
    else if (col == 2048) v = dist;
    else if (col < 3073) { int d = col - 2049; v = emo[d] * y[d]; }
    else if (col < 3123) v = dis[((size_t)e * NCC + c) * PPP + (col - 3073)];
    else if (col < 3173) v = ex;
    else v = 0.f;
    out[col] = v;
  }
}

__global__ __launch_bounds__(256) void k_p3(const float* __restrict__ h3,
                                            const float* __restrict__ bm, const float* __restrict__ bi,
                                            const float* __restrict__ cw, const float* __restrict__ cb,
                                            float* __restrict__ out) {
  int e = blockIdx.x >> 7, c = blockIdx.x & 127;
  int tid = threadIdx.x;
  const float* row = h3 + ((size_t)e * NCC + c) * DD;
  float l0 = 0, l1 = 0;
  for (int col = tid; col < DD; col += 256) {
    float h = leakyf((row[col] - bm[e * DD + col]) * bi[e * DD + col]);
    l0 += h * cw[col];
    l1 += h * cw[DD + col];
  }
  __shared__ float s4[4];
  l0 = blk_sum(l0, s4);
  l1 = blk_sum(l1, s4);
  if (tid == 0) {
    l0 += cb[0];
    l1 += cb[1];
    float mx = fmaxf(l0, l1);
    float lse = mx + logf(__expf(l0 - mx) + __expf(l1 - mx));
    out[((size_t)e * NCC + c) * 2 + 0] = l0 - lse;
    out[((size_t)e * NCC + c) * 2 + 1] = l1 - lse;
  }
}

__global__ __launch_bounds__(256) void k_L(const int* __restrict__ lab, float* __restrict__ out) {
  int i = blockIdx.x * 256 + threadIdx.x;  // 8192
  int e = i >> 7, c = i & 127;
  int a = lab[e * 3 + 0], b = lab[e * 3 + 1], d = lab[e * 3 + 2];
  out[i] = (a == c || b == c || d == c) ? 1.f : 0.f;
}

extern "C" void kernel_launch(void* const* d_in, const int* in_sizes, int n_in,
                              void* d_out, int out_size, void* d_ws, size_t ws_size,
                              hipStream_t stream) {
  (void)in_sizes; (void)n_in; (void)out_size; (void)ws_size;
  const float* X     = (const float*)d_in[0];
  const float* pos   = (const float*)d_in[1];
  const float* dis   = (const float*)d_in[2];
  const int*   lens  = (const int*)d_in[3];
  const int*   lab3  = (const int*)d_in[4];
  const int*   emoI  = (const int*)d_in[5];
  const int*   cauI  = (const int*)d_in[6];
  const float* Wih_f = (const float*)d_in[7];
  const float* Whh_f = (const float*)d_in[8];
  const float* bih_f = (const float*)d_in[9];
  const float* bhh_f = (const float*)d_in[10];
  const float* Wih_b = (const float*)d_in[11];
  const float* Whh_b = (const float*)d_in[12];
  const float* bih_b = (const float*)d_in[13];
  const float* bhh_b = (const float*)d_in[14];
  const float* s1w   = (const float*)d_in[15];
  const float* s1b   = (const float*)d_in[16];
  const float* s2w   = (const float*)d_in[17];
  const float* W2w   = (const float*)d_in[18];
  const float* W2b   = (const float*)d_in[19];
  const float* Wow   = (const float*)d_in[20];
  const float* Wob   = (const float*)d_in[21];
  const float* W3w   = (const float*)d_in[22];
  const float* W3b   = (const float*)d_in[23];
  const float* clsw  = (const float*)d_in[24];
  const float* clsb  = (const float*)d_in[25];
  float* ws = (float*)d_ws;
  float* out = (float*)d_out;

  unsigned short* Hhi = (unsigned short*)(ws + F_HSEQ);
  unsigned short* Hlo = Hhi + (size_t)NROWS * DD;
  unsigned short* WIHhi = (unsigned short*)(ws + F_WIH);
  unsigned short* WIHlo = WIHhi + (size_t)2 * 2048 * 1024;
  unsigned short* WHHhi = (unsigned short*)(ws + F_WHH);
  unsigned short* WHHlo = WHHhi + (size_t)2 * 2048 * 512;
  unsigned short* S1hi  = (unsigned short*)(ws + F_S1);
  unsigned short* S1lo  = S1hi + (size_t)1024 * 1024;
  unsigned short* W2hi  = (unsigned short*)(ws + F_W2);
  unsigned short* W2lo  = W2hi + (size_t)1024 * K3PAD;
  unsigned short* W3hi  = (unsigned short*)(ws + F_W3);
  unsigned short* W3lo  = W3hi + (size_t)1024 * K3PAD;

  // zero-init read-before-write buffers (padded Hseq rows MUST be 0 for BN stats)
  hipMemsetAsync(ws + F_HSEQ, 0, (size_t)33554432 * sizeof(float), stream);  // Hhi+Hlo
  hipMemsetAsync(ws + F_HST, 0, (size_t)(524288 + 262144) * sizeof(float), stream);  // HST + CST
  hipMemsetAsync(ws + F_CS, 0, (size_t)2048 * sizeof(float), stream);                // CS + CSQ
  hipMemsetAsync(ws + F_ALPHA, 0, (size_t)32768 * sizeof(float), stream);

  // weight converts (fp32 -> bf16 hi/lo, n-major = native torch layout)
  k_cvt<<<2048, 256, 0, stream>>>(Wih_f, WIHhi, WIHlo, 1024, 1024);
  k_cvt<<<2048, 256, 0, stream>>>(Wih_b, WIHhi + (size_t)2048 * 1024, WIHlo + (size_t)2048 * 1024, 1024, 1024);
  k_cvt<<<2048, 256, 0, stream>>>(Whh_f, WHHhi, WHHlo, 512, 512);
  k_cvt<<<2048, 256, 0, stream>>>(Whh_b, WHHhi + (size_t)2048 * 512, WHHlo + (size_t)2048 * 512, 512, 512);
  k_cvt<<<1024, 256, 0, stream>>>(s1w, S1hi, S1lo, 1024, 1024);
  k_cvt<<<1024, 256, 0, stream>>>(W2w, W2hi, W2lo, 3123, K3PAD);
  k_cvt<<<1024, 256, 0, stream>>>(W3w, W3hi, W3lo, 3173, K3PAD);
  k_biasc<<<16, 256, 0, stream>>>(bih_f, bhh_f, bih_b, bhh_b, ws + F_BIASC);

  // BiLSTM: chunked input-projection MFMA GEMMs + fused per-step rec kernel
  for (int c = 0; c < TT / CHUNK; ++c) {
    k_mf<3><<<dim3(16, 16, 2), 256, 0, stream>>>(X, nullptr, nullptr, WIHhi, WIHlo,
                                                 ws + F_BIASC, ws + F_XG,
                                                 2048, 2048, 1024, lens, c,
                                                 nullptr, nullptr, nullptr, nullptr, nullptr, nullptr);
    for (int tt = 0; tt < CHUNK; ++tt) {
      int t = c * CHUNK + tt;
      const float* Hcur = ws + F_HST + (size_t)(t & 1) * 262144;
      float* Hnext = ws + F_HST + (size_t)((t + 1) & 1) * 262144;
      k_rec<<<dim3(4, 32, 2), 256, 0, stream>>>(WHHhi, WHHlo, ws + F_XG, lens,
                                                Hcur, Hnext, ws + F_CST, Hhi, Hlo, t);
    }
  }

  // attention: two-pass z (BN stats, then masked-linear attention weights); A pre-split
  k_mf<1><<<dim3(256, 8), 256, 0, stream>>>(nullptr, Hhi, Hlo, S1hi, S1lo, s1b, nullptr,
                                            NROWS, 1024, 1024, nullptr, 0,
                                            nullptr, nullptr, nullptr,
                                            ws + F_CS, ws + F_CSQ, nullptr);
  k_bnfinal<<<4, 256, 0, stream>>>(ws + F_CS, ws + F_CSQ, ws + F_BNM, ws + F_BNI, 1.f / NROWS);
  k_mf<2><<<dim3(256, 8), 256, 0, stream>>>(nullptr, Hhi, Hlo, S1hi, S1lo, s1b, nullptr,
                                            NROWS, 1024, 1024, nullptr, 0,
                                            ws + F_BNM, ws + F_BNI, s2w,
                                            nullptr, nullptr, ws + F_ALPHA);
  k_asum<<<BB, TT, 0, stream>>>(ws + F_ALPHA, lens);
  k_U<<<BB, 256, 0, stream>>>(Hhi, Hlo, ws + F_ALPHA, ws + F_U);

  // phase 2 (D2/CHE overlay dead Hseq region)
  k_p2a<<<NE, 256, 0, stream>>>(ws + F_U, emoI, cauI, ws + F_CHE);
  k_delta2<<<NE * NCK, 256, 0, stream>>>(ws + F_U, emoI, ws + F_CHE, pos, ws + F_D2);
  k_mf<0><<<dim3(4, 8), 256, 0, stream>>>(ws + F_D2, nullptr, nullptr, W2hi, W2lo, W2b, ws + F_H2,
                                          512, 1024, K3PAD, nullptr, 0,
                                          nullptr, nullptr, nullptr, nullptr, nullptr, nullptr);
  k_bnstats<<<256, 256, 0, stream>>>(ws + F_H2, ws + F_BN2M, ws + F_BN2I, NCK);
  k_out2<<<NE * NCK, 256, 0, stream>>>(ws + F_H2, ws + F_BN2M, ws + F_BN2I, Wow, Wob,
                                       out, ws + F_EXTRA);

  // phase 3 (D3 overlays Hseq; H3 overlays dead XG)
  k_delta3<<<NE * NCC, 256, 0, stream>>>(ws + F_U, emoI, cauI, dis, ws + F_EXTRA, ws + F_D3);
  k_mf<0><<<dim3(64, 8), 256, 0, stream>>>(ws + F_D3, nullptr, nullptr, W3hi, W3lo, W3b, ws + F_H3,
                                           8192, 1024, K3PAD, nullptr, 0,
                                           nullptr, nullptr, nullptr, nullptr, nullptr, nullptr);
  k_bnstats<<<256, 256, 0, stream>>>(ws + F_H3, ws + F_BN3M, ws + F_BN3I, NCC);
  k_p3<<<NE * NCC, 256, 0, stream>>>(ws + F_H3, ws + F_BN3M, ws + F_BN3I, clsw, clsb, out + 1024);
  k_L<<<32, 256, 0, stream>>>(lab3, out + 17408);
}